// Round 2
// baseline (13410.510 us; speedup 1.0000x reference)
//
#include <hip/hip_runtime.h>
#include <math.h>

// TransformerVAE forward, fp32 (round 1: fix workspace overrun from round 0).
// B=64, S=512, INP=64, D=512, H=8, dk=64, L=2, DFF=2048, LAT=128, topk=6.
// Token layout: t = s*B + b, i.e. (S,B,D) row-major (matches reference).
// Attention runs across the batch axis per (s, head).
//
// Workspace budget: 2 x 64MB activation buffers (ping-pong) + 512KB extras.
// LN never materialized: stats_k stores per-row (mean, rstd); LN is applied
// in the A-loaders (gemm_k<LN=1>, attn_fused_k, pool_ln_k). FFN accumulates
// into the *other* buffer (cur/alt swap per layer) so f1 chunks always read
// an unmodified h. FFN chunk scratch: 3rd ws buffer (512-wide) if ws_size
// allows, else the recon region of d_out (64-wide chunks).

#define SQRT_D 22.62741699796952f
#define PE_C   0.017988946039015984f   // ln(10000)/512

__device__ __forceinline__ float pe_val(int s, int d) {
    float div = expf(-(float)(d & ~1) * PE_C);
    float ang = (float)s * div;
    return (d & 1) ? cosf(ang) : sinf(ang);
}

__device__ __forceinline__ float gelu_exact(float x) {
    return 0.5f * x * (1.0f + erff(x * 0.7071067811865476f));
}

// ---------------------------------------------------------------- embed (enc)
__global__ __launch_bounds__(256) void embed_enc_k(
    const float* __restrict__ x, const float* __restrict__ W,
    const float* __restrict__ bias, float* __restrict__ h)
{
    const int t = blockIdx.x;          // 0..32767
    const int s = t >> 6, b = t & 63;
    const int tid = threadIdx.x;
    __shared__ float xs[64];
    if (tid < 64) xs[tid] = x[((size_t)b * 512 + s) * 64 + tid];
    __syncthreads();
#pragma unroll
    for (int u = 0; u < 2; u++) {
        int d = tid + u * 256;
        float acc = bias[d];
        for (int i = 0; i < 64; i++) acc += xs[i] * W[i * 512 + d];
        h[(size_t)t * 512 + d] = acc * SQRT_D + pe_val(s, d);
    }
}

// ---------------------------------------------------------------- embed (dec)
__global__ __launch_bounds__(256) void dec_embed_k(
    const float* __restrict__ zemb, float* __restrict__ h)
{
    int idx = blockIdx.x * 256 + threadIdx.x;   // 16.7M elems
    int d = idx & 511;
    int t = idx >> 9;
    int s = t >> 6, b = t & 63;
    h[idx] = zemb[b * 512 + d] * SQRT_D + pe_val(s, d);
}

// ---------------------------------------------------------------- LN stats
// st[row*2] = mean, st[row*2+1] = rstd (two-pass, matches reference numerics)
__global__ __launch_bounds__(256) void stats_k(
    const float* __restrict__ x, float* __restrict__ st)
{
    const int row = blockIdx.x;
    const int tid = threadIdx.x;
    const float* xr = x + (size_t)row * 512;
    float v0 = xr[tid], v1 = xr[tid + 256];
    float ssum = v0 + v1;
#pragma unroll
    for (int off = 32; off > 0; off >>= 1) ssum += __shfl_down(ssum, off, 64);
    __shared__ float red[4];
    __shared__ float red2[4];
    const int wid = tid >> 6, lane = tid & 63;
    if (lane == 0) red[wid] = ssum;
    __syncthreads();
    float m = (red[0] + red[1] + red[2] + red[3]) * (1.f / 512.f);
    float d0 = v0 - m, d1 = v1 - m;
    float s2 = d0 * d0 + d1 * d1;
#pragma unroll
    for (int off = 32; off > 0; off >>= 1) s2 += __shfl_down(s2, off, 64);
    if (lane == 0) red2[wid] = s2;
    __syncthreads();
    if (tid == 0) {
        float var = (red2[0] + red2[1] + red2[2] + red2[3]) * (1.f / 512.f);
        st[row * 2]     = m;
        st[row * 2 + 1] = rsqrtf(var + 1e-5f);
    }
}

// ---------------------------------------------------------------- GEMM
// C[M,N] = op(A)[M,K] @ W[K,N] (+bias) (gelu?) (+res).  64x64 tile, BK=16.
// LN==1: A elements become (A-m)*rstd*lng[k]+lnb[k] on load.
// PERM==1: row t=(s*64+b) stored to C[(b*512+s)*ldc + c].
// res/C may alias element-wise (same thread read->write).
template<int ACT, int PERM, int LN>
__global__ __launch_bounds__(256) void gemm_k(
    const float* __restrict__ A, int lda,
    const float* __restrict__ W, int ldw,
    const float* __restrict__ bias,
    const float* res,
    float* C, int ldc,
    int K,
    const float* __restrict__ stats,
    const float* __restrict__ lng, const float* __restrict__ lnb)
{
    __shared__ float As[16][68];
    __shared__ float Ws[16][68];
    __shared__ float ms[64], rss[64];
    const int row0 = blockIdx.y * 64;
    const int col0 = blockIdx.x * 64;
    const int tid = threadIdx.x;
    if (LN) {
        if (tid < 64) {
            ms[tid]  = stats[(row0 + tid) * 2];
            rss[tid] = stats[(row0 + tid) * 2 + 1];
        }
        __syncthreads();
    }
    const int tm = (tid >> 4) << 2;
    const int tn = (tid & 15) << 2;
    float acc[4][4] = {};
    for (int k0 = 0; k0 < K; k0 += 16) {
#pragma unroll
        for (int i = 0; i < 4; i++) {
            int idx = i * 256 + tid;
            int r = idx >> 4, kk = idx & 15;
            float v = A[(size_t)(row0 + r) * lda + (k0 + kk)];
            if (LN) v = (v - ms[r]) * rss[r] * lng[k0 + kk] + lnb[k0 + kk];
            As[kk][r] = v;
        }
#pragma unroll
        for (int i = 0; i < 4; i++) {
            int idx = i * 256 + tid;
            int kk = idx >> 6, c = idx & 63;
            Ws[kk][c] = W[(size_t)(k0 + kk) * ldw + (col0 + c)];
        }
        __syncthreads();
#pragma unroll
        for (int kk = 0; kk < 16; kk++) {
            float4 a4 = *reinterpret_cast<const float4*>(&As[kk][tm]);
            float4 b4 = *reinterpret_cast<const float4*>(&Ws[kk][tn]);
            const float a[4] = {a4.x, a4.y, a4.z, a4.w};
            const float b[4] = {b4.x, b4.y, b4.z, b4.w};
#pragma unroll
            for (int i = 0; i < 4; i++)
#pragma unroll
                for (int j = 0; j < 4; j++)
                    acc[i][j] += a[i] * b[j];
        }
        __syncthreads();
    }
#pragma unroll
    for (int i = 0; i < 4; i++) {
        int r = row0 + tm + i;
#pragma unroll
        for (int j = 0; j < 4; j++) {
            int c = col0 + tn + j;
            float v = acc[i][j];
            if (bias) v += bias[c];
            if (ACT == 1) v = gelu_exact(v);
            if (res) v += res[(size_t)r * ldc + c];
            if (PERM) {
                int bb = r & 63, ss = r >> 6;
                C[((size_t)bb * 512 + ss) * ldc + c] = v;
            } else {
                C[(size_t)r * ldc + c] = v;
            }
        }
    }
}

// ---------------------------------------------------------------- attention
// One block per (s, head). Phase 1: q,k,v = LN(h_tile) @ {wq,wk,wv}[:,head]
// accumulated in registers (K-chunks of 32 staged in LDS). Phase 2: scores,
// top-6 threshold (>= kth kept, ties kept), softmax (masked = exact 0), PV.
// LDS: 48KB compute arrays (staging overlaid) + 512B stats.
__global__ __launch_bounds__(256) void attn_fused_k(
    const float* __restrict__ h, const float* __restrict__ st,
    const float* __restrict__ g1, const float* __restrict__ b1,
    const float* __restrict__ wq, const float* __restrict__ wk,
    const float* __restrict__ wv, float* __restrict__ ctx)
{
    __shared__ float smem[12288];          // 48 KB
    __shared__ float ms[64], rss[64];
    const int blk = blockIdx.x;            // 0..4095
    const int s = blk >> 3, hh = blk & 7;
    const int tid = threadIdx.x;
    const int row0 = s * 64;
    const int col0 = hh * 64;
    const int tm = (tid >> 4) << 2;
    const int tn = (tid & 15) << 2;

    float* Hs  = smem;                     // [64][33] padded (2112 floats)
    float* Wqs = smem + 2112;              // [32][64]
    float* Wks = smem + 4160;              // [32][64]
    float* Wvs = smem + 6208;              // [32][64]

    if (tid < 64) {
        ms[tid]  = st[(row0 + tid) * 2];
        rss[tid] = st[(row0 + tid) * 2 + 1];
    }
    float aq[4][4] = {}, ak[4][4] = {}, av[4][4] = {};
    for (int kc = 0; kc < 512; kc += 32) {
        __syncthreads();   // staging area free (also covers ms preload)
#pragma unroll
        for (int i = 0; i < 8; i++) {
            int idx = i * 256 + tid;
            {
                int rr = idx >> 5, cc = idx & 31;
                float v = h[(size_t)(row0 + rr) * 512 + (kc + cc)];
                Hs[rr * 33 + cc] = (v - ms[rr]) * rss[rr] * g1[kc + cc] + b1[kc + cc];
            }
            {
                int rr = idx >> 6, cc = idx & 63;
                size_t widx = (size_t)(kc + rr) * 512 + (col0 + cc);
                Wqs[rr * 64 + cc] = wq[widx];
                Wks[rr * 64 + cc] = wk[widx];
                Wvs[rr * 64 + cc] = wv[widx];
            }
        }
        __syncthreads();
#pragma unroll 4
        for (int kk = 0; kk < 32; kk++) {
            float a[4];
#pragma unroll
            for (int i = 0; i < 4; i++) a[i] = Hs[(tm + i) * 33 + kk];
            float4 q4 = *reinterpret_cast<const float4*>(&Wqs[kk * 64 + tn]);
            float4 k4 = *reinterpret_cast<const float4*>(&Wks[kk * 64 + tn]);
            float4 v4 = *reinterpret_cast<const float4*>(&Wvs[kk * 64 + tn]);
            const float qb[4] = {q4.x, q4.y, q4.z, q4.w};
            const float kb[4] = {k4.x, k4.y, k4.z, k4.w};
            const float vb[4] = {v4.x, v4.y, v4.z, v4.w};
#pragma unroll
            for (int i = 0; i < 4; i++)
#pragma unroll
                for (int j = 0; j < 4; j++) {
                    aq[i][j] += a[i] * qb[j];
                    ak[i][j] += a[i] * kb[j];
                    av[i][j] += a[i] * vb[j];
                }
        }
    }
    __syncthreads();       // staging reads done; reuse LDS for phase 2
    float (*QT)[64] = (float(*)[64])smem;            // Q^T [dim][batch-row]
    float (*KT)[64] = (float(*)[64])(smem + 4096);   // K^T [dim][batch-col]
    float (*Vs)[64] = (float(*)[64])(smem + 8192);   // V   [batch][dim]
#pragma unroll
    for (int i = 0; i < 4; i++) {
#pragma unroll
        for (int j = 0; j < 4; j++) {
            QT[tn + j][tm + i] = aq[i][j];
            KT[tn + j][tm + i] = ak[i][j];
        }
        *reinterpret_cast<float4*>(&Vs[tm + i][tn]) =
            make_float4(av[i][0], av[i][1], av[i][2], av[i][3]);
    }
    __syncthreads();
    float sc[4][4] = {};
#pragma unroll 4
    for (int kk = 0; kk < 64; kk++) {
        float4 a4 = *reinterpret_cast<const float4*>(&QT[kk][tm]);
        float4 b4 = *reinterpret_cast<const float4*>(&KT[kk][tn]);
        const float a[4] = {a4.x, a4.y, a4.z, a4.w};
        const float b[4] = {b4.x, b4.y, b4.z, b4.w};
#pragma unroll
        for (int i = 0; i < 4; i++)
#pragma unroll
            for (int j = 0; j < 4; j++)
                sc[i][j] += a[i] * b[j];
    }
    __syncthreads();       // KT reads done; reuse as ScT
    float (*ScT)[64] = KT; // scores^T [col][row]
#pragma unroll
    for (int i = 0; i < 4; i++)
#pragma unroll
        for (int j = 0; j < 4; j++)
            ScT[tn + j][tm + i] = sc[i][j] * 0.125f;
    __syncthreads();
    if (tid < 64) {        // top-6 + softmax, one thread per row
        const int row = tid;
        float top[6];
#pragma unroll
        for (int i = 0; i < 6; i++) top[i] = -3.4e38f;
        for (int c = 0; c < 64; c++) {
            float vv = ScT[c][row];
            if (vv > top[5]) {
                top[5] = vv;
#pragma unroll
                for (int i = 5; i > 0; i--)
                    if (top[i] > top[i - 1]) { float t = top[i]; top[i] = top[i - 1]; top[i - 1] = t; }
            }
        }
        const float thresh = top[5], m = top[0];
        float denom = 0.f;
        for (int c = 0; c < 64; c++) {
            float vv = ScT[c][row];
            float w = (vv >= thresh) ? expf(vv - m) : 0.f;
            denom += w;
            QT[c][row] = w;            // P^T (QT space free after score GEMM)
        }
        float rd = 1.f / denom;
        for (int c = 0; c < 64; c++) QT[c][row] *= rd;
    }
    __syncthreads();
    {   // ctx[r][j] = sum_c P[r][c] * V[c][j]
        float acc[4][4] = {};
#pragma unroll 4
        for (int c = 0; c < 64; c++) {
            float4 p4 = *reinterpret_cast<const float4*>(&QT[c][tm]);
            float4 v4 = *reinterpret_cast<const float4*>(&Vs[c][tn]);
            const float p[4] = {p4.x, p4.y, p4.z, p4.w};
            const float b[4] = {v4.x, v4.y, v4.z, v4.w};
#pragma unroll
            for (int i = 0; i < 4; i++)
#pragma unroll
                for (int j = 0; j < 4; j++)
                    acc[i][j] += p[i] * b[j];
        }
#pragma unroll
        for (int i = 0; i < 4; i++) {
            float4 o = make_float4(acc[i][0], acc[i][1], acc[i][2], acc[i][3]);
            *reinterpret_cast<float4*>(
                &ctx[(size_t)(row0 + tm + i) * 512 + (col0 + tn)]) = o;
        }
    }
}

// ---------------------------------------------------------------- pool (+LN)
// pooled[b,d] = mean_s LN(h[(s*64+b), d]) with gf,bf
__global__ __launch_bounds__(512) void pool_ln_k(
    const float* __restrict__ h, const float* __restrict__ st,
    const float* __restrict__ gf, const float* __restrict__ bf,
    float* __restrict__ pooled)
{
    const int b = blockIdx.x;
    const int d = threadIdx.x;
    const float g = gf[d], bb = bf[d];
    float acc = 0.f;
    for (int s = 0; s < 512; s++) {
        int r = s * 64 + b;
        float m = st[r * 2], rs = st[r * 2 + 1];
        acc += (h[(size_t)r * 512 + d] - m) * rs * g + bb;
    }
    pooled[b * 512 + d] = acc * (1.f / 512.f);
}

// ---------------------------------------------------------------- host side
static void run_layer(const float* g1, const float* b1, const float* wq,
                      const float* wk, const float* wv, const float* woW,
                      const float* wob, const float* g2, const float* b2,
                      const float* f1W, const float* f1b, const float* f2W,
                      const float* f2b, float*& cur, float*& alt,
                      float* stats, float* chunk, int cw, hipStream_t stream)
{
    const int M = 32768;
    dim3 g8(8, M / 64);
    // attention block
    stats_k<<<M, 256, 0, stream>>>(cur, stats);
    attn_fused_k<<<4096, 256, 0, stream>>>(cur, stats, g1, b1, wq, wk, wv, alt);
    gemm_k<0, 0, 0><<<g8, 256, 0, stream>>>(alt, 512, woW, 512, wob, cur, cur, 512, 512,
                                            nullptr, nullptr, nullptr);
    // FFN block: accumulate into alt (so f1 chunks always read unmodified cur)
    stats_k<<<M, 256, 0, stream>>>(cur, stats);
    const int nch = 2048 / cw;
    for (int c = 0; c < nch; c++) {
        gemm_k<1, 0, 1><<<dim3(cw / 64, M / 64), 256, 0, stream>>>(
            cur, 512, f1W + c * cw, 2048, f1b + c * cw, nullptr, chunk, cw, 512,
            stats, g2, b2);
        gemm_k<0, 0, 0><<<g8, 256, 0, stream>>>(
            chunk, cw, f2W + (size_t)(c * cw) * 512, 512,
            (c == 0) ? f2b : nullptr, (c == 0) ? cur : alt, alt, 512, cw,
            nullptr, nullptr, nullptr);
    }
    float* t = cur; cur = alt; alt = t;   // new h lives in alt
}

extern "C" void kernel_launch(void* const* d_in, const int* in_sizes, int n_in,
                              void* d_out, int out_size, void* d_ws, size_t ws_size,
                              hipStream_t stream)
{
    // setup_inputs() dict order
    const float* x       = (const float*)d_in[0];
    const float* enc_inW = (const float*)d_in[1];
    const float* enc_inb = (const float*)d_in[2];
    const float* mu_W    = (const float*)d_in[3];
    const float* mu_b    = (const float*)d_in[4];
    const float* lv_W    = (const float*)d_in[5];
    const float* lv_b    = (const float*)d_in[6];
    const float* dec_inW = (const float*)d_in[7];
    const float* dec_inb = (const float*)d_in[8];
    const float* out_W   = (const float*)d_in[9];
    const float* out_b   = (const float*)d_in[10];
    const float* const* ep = (const float* const*)(d_in + 11);
    const float* const* dp = (const float* const*)(d_in + 26);

    float* fout   = (float*)d_out;             // recon (64,512,64) = 2097152
    float* mu_out = fout + 2097152;            // (64,128)
    float* lv_out = mu_out + 8192;             // (64,128)

    const size_t SZ = (size_t)32768 * 512;     // 64 MB per buffer
    float* bufA = (float*)d_ws;
    float* bufB = bufA + SZ;
    float* stats; float* chunk; int cw;
    const size_t need_wide = (3 * SZ + 131072) * sizeof(float);   // ~192.5 MB
    if (ws_size >= need_wide) {
        chunk = bufB + SZ; cw = 512;           // 3rd 64MB buffer for FFN chunks
        stats = chunk + SZ;
    } else {
        chunk = fout; cw = 64;                 // recon region = 8MB scratch
        stats = bufB + SZ;
    }
    float* pooled = stats + 65536;             // (64,512)
    float* zemb   = pooled + 32768;            // (64,512)

    const int M = 32768;
    float* cur = bufA;
    float* alt = bufB;

    // ---------------- encoder ----------------
    embed_enc_k<<<M, 256, 0, stream>>>(x, enc_inW, enc_inb, cur);
    for (int l = 0; l < 2; l++) {
        run_layer(ep[0] + l * 512, ep[1] + l * 512,
                  ep[2] + (size_t)l * 512 * 512, ep[3] + (size_t)l * 512 * 512,
                  ep[4] + (size_t)l * 512 * 512, ep[5] + (size_t)l * 512 * 512,
                  ep[6] + l * 512, ep[7] + l * 512, ep[8] + l * 512,
                  ep[9] + (size_t)l * 512 * 2048, ep[10] + l * 2048,
                  ep[11] + (size_t)l * 2048 * 512, ep[12] + l * 512,
                  cur, alt, stats, chunk, cw, stream);
    }

    // ---------------- latent ----------------
    stats_k<<<M, 256, 0, stream>>>(cur, stats);
    pool_ln_k<<<64, 512, 0, stream>>>(cur, stats, ep[13], ep[14], pooled);
    gemm_k<0, 0, 0><<<dim3(2, 1), 256, 0, stream>>>(pooled, 512, mu_W, 128, mu_b,
                                                    nullptr, mu_out, 128, 512,
                                                    nullptr, nullptr, nullptr);
    gemm_k<0, 0, 0><<<dim3(2, 1), 256, 0, stream>>>(pooled, 512, lv_W, 128, lv_b,
                                                    nullptr, lv_out, 128, 512,
                                                    nullptr, nullptr, nullptr);
    gemm_k<0, 0, 0><<<dim3(8, 1), 256, 0, stream>>>(mu_out, 128, dec_inW, 512, dec_inb,
                                                    nullptr, zemb, 512, 128,
                                                    nullptr, nullptr, nullptr);
    dec_embed_k<<<65536, 256, 0, stream>>>(zemb, cur);

    // ---------------- decoder ----------------
    for (int l = 0; l < 2; l++) {
        run_layer(dp[0] + l * 512, dp[1] + l * 512,
                  dp[2] + (size_t)l * 512 * 512, dp[3] + (size_t)l * 512 * 512,
                  dp[4] + (size_t)l * 512 * 512, dp[5] + (size_t)l * 512 * 512,
                  dp[6] + l * 512, dp[7] + l * 512, dp[8] + l * 512,
                  dp[9] + (size_t)l * 512 * 2048, dp[10] + l * 2048,
                  dp[11] + (size_t)l * 2048 * 512, dp[12] + l * 512,
                  cur, alt, stats, chunk, cw, stream);
    }

    // final LN + out-proj, stored as (B,S,INP)
    stats_k<<<M, 256, 0, stream>>>(cur, stats);
    gemm_k<0, 1, 1><<<dim3(1, M / 64), 256, 0, stream>>>(
        cur, 512, out_W, 64, out_b, nullptr, fout, 64, 512, stats, dp[13], dp[14]);
}

// Round 3
// 3750.441 us; speedup vs baseline: 3.5757x; 3.5757x over previous
//
#include <hip/hip_runtime.h>
#include <math.h>

// TransformerVAE forward — round 2: bf16 MFMA GEMMs.
// B=64, S=512, INP=64, D=512, H=8, dk=64, L=2, DFF=2048, LAT=128, topk=6.
// Token layout: t = s*64 + b ((S,B,D) row-major). Attention across batch axis.
//
// Structure per layer:
//   cast_ln_k: hn_bf = bf16(LN(h, g1,b1))            [fp32 h kept as residual]
//   mgemm QKV: qkv = hn_bf @ [wq|wk|wv]^T_bf16       (N=1536, bf16 out)
//   attn2_k:   ctx(bf16, into hn_bf) = topk-softmax attention per (s,head)
//   mgemm wo:  h += ctx @ wo + wob                   (fp32 out, residual fused)
//   cast_ln_k: hn_bf = bf16(LN(h, g2,b2))
//   mgemm f1:  f1c = gelu(hn_bf @ f1W + f1b)         (bf16 out, chunked)
//   mgemm f2:  h += f1c @ f2W (+f2b on chunk 0)      (fp32 out, residual fused)
// Weights are transpose-cast to bf16 [N][K] per layer (MFMA B-frag wants
// contiguous K per lane; this is the m97 "B^T input" trick).

#define SQRT_D 22.62741699796952f
#define PE_C   0.017988946039015984f   // ln(10000)/512

typedef short frag8 __attribute__((ext_vector_type(8)));   // 8 bf16
typedef float accf4 __attribute__((ext_vector_type(4)));   // 4 fp32 acc

#define GLL16(g, l) __builtin_amdgcn_global_load_lds( \
    (const __attribute__((address_space(1))) void*)(g), \
    (__attribute__((address_space(3))) void*)(l), 16, 0, 0)

__device__ __forceinline__ float bf2f(unsigned short u) {
    union { unsigned i; float f; } v; v.i = ((unsigned)u) << 16; return v.f;
}
__device__ __forceinline__ unsigned short f2bf(float f) {   // RNE
    union { float f; unsigned i; } v; v.f = f;
    unsigned r = v.i + 0x7fff + ((v.i >> 16) & 1);
    return (unsigned short)(r >> 16);
}
__device__ __forceinline__ float pe_val(int s, int d) {
    float div = expf(-(float)(d & ~1) * PE_C);
    float ang = (float)s * div;
    return (d & 1) ? cosf(ang) : sinf(ang);
}
__device__ __forceinline__ float gelu_exact(float x) {
    return 0.5f * x * (1.0f + erff(x * 0.7071067811865476f));
}

// ---------------------------------------------------------------- embed (enc)
__global__ __launch_bounds__(256) void embed_enc_k(
    const float* __restrict__ x, const float* __restrict__ W,
    const float* __restrict__ bias, float* __restrict__ h)
{
    const int t = blockIdx.x;          // 0..32767
    const int s = t >> 6, b = t & 63;
    const int tid = threadIdx.x;
    __shared__ float xs[64];
    if (tid < 64) xs[tid] = x[((size_t)b * 512 + s) * 64 + tid];
    __syncthreads();
#pragma unroll
    for (int u = 0; u < 2; u++) {
        int d = tid + u * 256;
        float acc = bias[d];
        for (int i = 0; i < 64; i++) acc += xs[i] * W[i * 512 + d];
        h[(size_t)t * 512 + d] = acc * SQRT_D + pe_val(s, d);
    }
}

// ---------------------------------------------------------------- embed (dec)
__global__ __launch_bounds__(256) void dec_embed_k(
    const float* __restrict__ zemb, float* __restrict__ h)
{
    int idx = blockIdx.x * 256 + threadIdx.x;   // 16.7M elems
    int d = idx & 511;
    int t = idx >> 9;
    int s = t >> 6;
    int b = t & 63;
    h[idx] = zemb[b * 512 + d] * SQRT_D + pe_val(s, d);
}

// ---------------------------------------------------------------- LN stats
__global__ __launch_bounds__(256) void stats_k(
    const float* __restrict__ x, float* __restrict__ st)
{
    const int row = blockIdx.x;
    const int tid = threadIdx.x;
    const float* xr = x + (size_t)row * 512;
    float v0 = xr[tid], v1 = xr[tid + 256];
    float ssum = v0 + v1;
#pragma unroll
    for (int off = 32; off > 0; off >>= 1) ssum += __shfl_down(ssum, off, 64);
    __shared__ float red[4];
    __shared__ float red2[4];
    const int wid = tid >> 6, lane = tid & 63;
    if (lane == 0) red[wid] = ssum;
    __syncthreads();
    float m = (red[0] + red[1] + red[2] + red[3]) * (1.f / 512.f);
    float d0 = v0 - m, d1 = v1 - m;
    float s2 = d0 * d0 + d1 * d1;
#pragma unroll
    for (int off = 32; off > 0; off >>= 1) s2 += __shfl_down(s2, off, 64);
    if (lane == 0) red2[wid] = s2;
    __syncthreads();
    if (tid == 0) {
        float var = (red2[0] + red2[1] + red2[2] + red2[3]) * (1.f / 512.f);
        st[row * 2]     = m;
        st[row * 2 + 1] = rsqrtf(var + 1e-5f);
    }
}

// ---------------------------------------------------------------- LN -> bf16
__global__ __launch_bounds__(256) void cast_ln_k(
    const float* __restrict__ x, const float* __restrict__ g,
    const float* __restrict__ b, unsigned short* __restrict__ y)
{
    const int row = blockIdx.x;
    const int tid = threadIdx.x;
    const float* xr = x + (size_t)row * 512;
    float v0 = xr[tid], v1 = xr[tid + 256];
    float ssum = v0 + v1;
#pragma unroll
    for (int off = 32; off > 0; off >>= 1) ssum += __shfl_down(ssum, off, 64);
    __shared__ float red[4];
    __shared__ float red2[4];
    const int wid = tid >> 6, lane = tid & 63;
    if (lane == 0) red[wid] = ssum;
    __syncthreads();
    float m = (red[0] + red[1] + red[2] + red[3]) * (1.f / 512.f);
    float d0 = v0 - m, d1 = v1 - m;
    float s2 = d0 * d0 + d1 * d1;
#pragma unroll
    for (int off = 32; off > 0; off >>= 1) s2 += __shfl_down(s2, off, 64);
    if (lane == 0) red2[wid] = s2;
    __syncthreads();
    float var = (red2[0] + red2[1] + red2[2] + red2[3]) * (1.f / 512.f);
    float rstd = rsqrtf(var + 1e-5f);
    unsigned short* yr = y + (size_t)row * 512;
    yr[tid]       = f2bf(d0 * rstd * g[tid] + b[tid]);
    yr[tid + 256] = f2bf(d1 * rstd * g[tid + 256] + b[tid + 256]);
}

// ------------------------------------------------------- weight transpose+cast
// W[Kd][Nd] fp32 -> Wt[Nd][Kd] bf16.  grid (Nd/32, Kd/32), 256 threads.
__global__ __launch_bounds__(256) void wtcast_k(
    const float* __restrict__ W, int Kd, int Nd, unsigned short* __restrict__ Wt)
{
    __shared__ float t[32][33];
    const int tx = threadIdx.x & 31, ty = threadIdx.x >> 5;   // ty 0..7
    const int n0 = blockIdx.x * 32, k0 = blockIdx.y * 32;
#pragma unroll
    for (int i = 0; i < 32; i += 8)
        t[ty + i][tx] = W[(size_t)(k0 + ty + i) * Nd + (n0 + tx)];
    __syncthreads();
#pragma unroll
    for (int i = 0; i < 32; i += 8)
        Wt[(size_t)(n0 + ty + i) * Kd + (k0 + tx)] = f2bf(t[tx][ty + i]);
}

// ---------------------------------------------------------------- MFMA GEMM
// C[M,N] = A[M,K](bf16) @ Bt[N,K](bf16)^T (+bias)(gelu?)(+fp32 res).
// 128x128 tile, BK=32, 256 threads = 4 waves (2x2), 4x4 16x16x32 MFMA / wave.
// Staging via global_load_lds width=16 (LDS layout = plain row-major [128][32],
// contiguous in wave-lane order — required by the wave-uniform-base DMA).
// res/Cf may alias element-wise (same thread read->write).
template<int ACT, int OUTBF, int RES, int BIAS>
__global__ __launch_bounds__(256) void mgemm_k(
    const unsigned short* __restrict__ A, int lda,
    const unsigned short* __restrict__ Bt, int ldb,
    const float* __restrict__ bias,
    const float* res, float* Cf, unsigned short* Cb, int ldc, int K)
{
    __shared__ unsigned short As[128 * 32];
    __shared__ unsigned short Bs[128 * 32];
    const int tid = threadIdx.x;
    const int wave = tid >> 6, lane = tid & 63;
    const int row0 = blockIdx.y * 128;
    const int col0 = blockIdx.x * 128;
    const int wr = wave >> 1, wc = wave & 1;
    accf4 acc[4][4] = {};
    const int srow = lane >> 2;            // 16 rows per 1KB chunk
    const int scol = (lane & 3) * 8;       // 8 bf16 = 16B per lane
    const unsigned short* gA = A + (size_t)(row0 + srow) * lda + scol;
    const unsigned short* gB = Bt + (size_t)(col0 + srow) * ldb + scol;
    const int frow = lane & 15, fk = (lane >> 4) * 8;
    for (int k0 = 0; k0 < K; k0 += 32) {
#pragma unroll
        for (int r = 0; r < 2; r++) {
            int c = wave * 2 + r;          // chunk 0..7 (16 rows each)
            GLL16(gA + (size_t)c * 16 * lda + k0, As + c * 512 + lane * 8);
            GLL16(gB + (size_t)c * 16 * ldb + k0, Bs + c * 512 + lane * 8);
        }
        __syncthreads();
        frag8 af[4], bfr[4];
#pragma unroll
        for (int i = 0; i < 4; i++)
            af[i] = *(const frag8*)&As[(wr * 64 + i * 16 + frow) * 32 + fk];
#pragma unroll
        for (int j = 0; j < 4; j++)
            bfr[j] = *(const frag8*)&Bs[(wc * 64 + j * 16 + frow) * 32 + fk];
#pragma unroll
        for (int i = 0; i < 4; i++)
#pragma unroll
            for (int j = 0; j < 4; j++)
                acc[i][j] = __builtin_amdgcn_mfma_f32_16x16x32_bf16(
                    af[i], bfr[j], acc[i][j], 0, 0, 0);
        __syncthreads();
    }
    // C/D layout: col = lane&15, row = (lane>>4)*4 + reg  [m89/m91 verified]
    const int lrow = (lane >> 4) * 4;
    const int lcol = lane & 15;
#pragma unroll
    for (int i = 0; i < 4; i++) {
#pragma unroll
        for (int reg = 0; reg < 4; reg++) {
            int r = row0 + wr * 64 + i * 16 + lrow + reg;
#pragma unroll
            for (int j = 0; j < 4; j++) {
                int c = col0 + wc * 64 + j * 16 + lcol;
                float v = acc[i][j][reg];
                if (BIAS) v += bias[c];
                if (ACT) v = gelu_exact(v);
                if (RES) v += res[(size_t)r * ldc + c];
                if (OUTBF) Cb[(size_t)r * ldc + c] = f2bf(v);
                else       Cf[(size_t)r * ldc + c] = v;
            }
        }
    }
}

// ---------------------------------------------------------------- attention
// One block per (s_local, head). Reads bf16 q,k,v from the fused qkv buffer
// (cols 0..511=q, 512..1023=k, 1024..1535=v), computes 64x64 scores over the
// batch axis, top-6 row threshold (>= kth kept, ties kept), softmax (masked =
// exact 0), PV; writes bf16 ctx. LDS stride 68 breaks the round-1 64-way
// transposed-store conflict (1.9e7 SQ_LDS_BANK_CONFLICT).
__global__ __launch_bounds__(256) void attn2_k(
    const unsigned short* __restrict__ qkv, unsigned short* __restrict__ ctx)
{
    __shared__ float QT[64][68];   // Q^T [dim][row]; later P^T [col][row]
    __shared__ float KT[64][68];   // K^T [dim][col]; later scores^T [col][row]
    __shared__ float Vs[64][68];   // V   [col][dim]
    const int blk = blockIdx.x;
    const int sl = blk >> 3, hh = blk & 7;
    const int tid = threadIdx.x;
    const size_t qbase = (size_t)sl * 64 * 1536 + (size_t)hh * 64;
#pragma unroll
    for (int i = 0; i < 16; i++) {
        int idx = i * 256 + tid;
        int rr = idx >> 6, cc = idx & 63;   // lanes vary cc (coalesced-ish)
        const size_t g = qbase + (size_t)rr * 1536 + cc;
        QT[cc][rr] = bf2f(qkv[g]);
        KT[cc][rr] = bf2f(qkv[g + 512]);
        Vs[rr][cc] = bf2f(qkv[g + 1024]);
    }
    __syncthreads();
    const int tm = (tid >> 4) << 2;
    const int tn = (tid & 15) << 2;
    float sc[4][4] = {};
#pragma unroll 4
    for (int kk = 0; kk < 64; kk++) {
        float4 a4 = *reinterpret_cast<const float4*>(&QT[kk][tm]);
        float4 b4 = *reinterpret_cast<const float4*>(&KT[kk][tn]);
        const float a[4] = {a4.x, a4.y, a4.z, a4.w};
        const float b[4] = {b4.x, b4.y, b4.z, b4.w};
#pragma unroll
        for (int i = 0; i < 4; i++)
#pragma unroll
            for (int j = 0; j < 4; j++)
                sc[i][j] += a[i] * b[j];
    }
    __syncthreads();           // KT reads done; reuse as ScT
    float (*ScT)[68] = KT;     // scores^T [col][row]
#pragma unroll
    for (int i = 0; i < 4; i++)
#pragma unroll
        for (int j = 0; j < 4; j++)
            ScT[tn + j][tm + i] = sc[i][j] * 0.125f;
    __syncthreads();
    if (tid < 64) {            // top-6 + softmax, one thread per row
        const int row = tid;
        float top[6];
#pragma unroll
        for (int i = 0; i < 6; i++) top[i] = -3.4e38f;
        for (int c = 0; c < 64; c++) {
            float vv = ScT[c][row];
            if (vv > top[5]) {
                top[5] = vv;
#pragma unroll
                for (int i = 5; i > 0; i--)
                    if (top[i] > top[i - 1]) { float t = top[i]; top[i] = top[i - 1]; top[i - 1] = t; }
            }
        }
        const float thresh = top[5], m = top[0];
        float denom = 0.f;
        for (int c = 0; c < 64; c++) {
            float vv = ScT[c][row];
            float w = (vv >= thresh) ? expf(vv - m) : 0.f;
            denom += w;
            QT[c][row] = w;    // P^T (QT free after score GEMM)
        }
        float rd = 1.f / denom;
        for (int c = 0; c < 64; c++) QT[c][row] *= rd;
    }
    __syncthreads();
    {   // ctx[r][j] = sum_c P[r][c] * V[c][j]
        float acc[4][4] = {};
#pragma unroll 4
        for (int c = 0; c < 64; c++) {
            float4 p4 = *reinterpret_cast<const float4*>(&QT[c][tm]);
            float4 v4 = *reinterpret_cast<const float4*>(&Vs[c][tn]);
            const float p[4] = {p4.x, p4.y, p4.z, p4.w};
            const float b[4] = {v4.x, v4.y, v4.z, v4.w};
#pragma unroll
            for (int i = 0; i < 4; i++)
#pragma unroll
                for (int j = 0; j < 4; j++)
                    acc[i][j] += p[i] * b[j];
        }
#pragma unroll
        for (int i = 0; i < 4; i++) {
            ushort4 o;
            o.x = f2bf(acc[i][0]); o.y = f2bf(acc[i][1]);
            o.z = f2bf(acc[i][2]); o.w = f2bf(acc[i][3]);
            *reinterpret_cast<ushort4*>(
                &ctx[(size_t)(sl * 64 + tm + i) * 512 + hh * 64 + tn]) = o;
        }
    }
}

// ---------------------------------------------------------- fp32 GEMM (small)
template<int ACT, int PERM, int LN>
__global__ __launch_bounds__(256) void gemm_k(
    const float* __restrict__ A, int lda,
    const float* __restrict__ W, int ldw,
    const float* __restrict__ bias,
    const float* res,
    float* C, int ldc,
    int K,
    const float* __restrict__ stats,
    const float* __restrict__ lng, const float* __restrict__ lnb)
{
    __shared__ float As[16][68];
    __shared__ float Ws[16][68];
    __shared__ float ms[64], rss[64];
    const int row0 = blockIdx.y * 64;
    const int col0 = blockIdx.x * 64;
    const int tid = threadIdx.x;
    if (LN) {
        if (tid < 64) {
            ms[tid]  = stats[(row0 + tid) * 2];
            rss[tid] = stats[(row0 + tid) * 2 + 1];
        }
        __syncthreads();
    }
    const int tm = (tid >> 4) << 2;
    const int tn = (tid & 15) << 2;
    float acc[4][4] = {};
    for (int k0 = 0; k0 < K; k0 += 16) {
#pragma unroll
        for (int i = 0; i < 4; i++) {
            int idx = i * 256 + tid;
            int r = idx >> 4, kk = idx & 15;
            float v = A[(size_t)(row0 + r) * lda + (k0 + kk)];
            if (LN) v = (v - ms[r]) * rss[r] * lng[k0 + kk] + lnb[k0 + kk];
            As[kk][r] = v;
        }
#pragma unroll
        for (int i = 0; i < 4; i++) {
            int idx = i * 256 + tid;
            int kk = idx >> 6, c = idx & 63;
            Ws[kk][c] = W[(size_t)(k0 + kk) * ldw + (col0 + c)];
        }
        __syncthreads();
#pragma unroll
        for (int kk = 0; kk < 16; kk++) {
            float4 a4 = *reinterpret_cast<const float4*>(&As[kk][tm]);
            float4 b4 = *reinterpret_cast<const float4*>(&Ws[kk][tn]);
            const float a[4] = {a4.x, a4.y, a4.z, a4.w};
            const float b[4] = {b4.x, b4.y, b4.z, b4.w};
#pragma unroll
            for (int i = 0; i < 4; i++)
#pragma unroll
                for (int j = 0; j < 4; j++)
                    acc[i][j] += a[i] * b[j];
        }
        __syncthreads();
    }
#pragma unroll
    for (int i = 0; i < 4; i++) {
        int r = row0 + tm + i;
#pragma unroll
        for (int j = 0; j < 4; j++) {
            int c = col0 + tn + j;
            float v = acc[i][j];
            if (bias) v += bias[c];
            if (ACT == 1) v = gelu_exact(v);
            if (res) v += res[(size_t)r * ldc + c];
            if (PERM) {
                int bb = r & 63, ss = r >> 6;
                C[((size_t)bb * 512 + ss) * ldc + c] = v;
            } else {
                C[(size_t)r * ldc + c] = v;
            }
        }
    }
}

// ---------------------------------------------------------------- pool (+LN)
__global__ __launch_bounds__(512) void pool_ln_k(
    const float* __restrict__ h, const float* __restrict__ st,
    const float* __restrict__ gf, const float* __restrict__ bf,
    float* __restrict__ pooled)
{
    const int b = blockIdx.x;
    const int d = threadIdx.x;
    const float g = gf[d], bb = bf[d];
    float acc = 0.f;
    for (int s = 0; s < 512; s++) {
        int r = s * 64 + b;
        float m = st[r * 2], rs = st[r * 2 + 1];
        acc += (h[(size_t)r * 512 + d] - m) * rs * g + bb;
    }
    pooled[b * 512 + d] = acc * (1.f / 512.f);
}

// ---------------------------------------------------------------- host side
static void run_layer2(const float* const* p, int l,
                       float* h, unsigned short* hn_bf,
                       unsigned short* qkv, int chunk_rows,
                       unsigned short* f1c, int cw,
                       unsigned short* wqkv_t, unsigned short* wo_t,
                       unsigned short* f1_t, unsigned short* f2_t,
                       hipStream_t stream)
{
    const float* g1  = p[0] + l * 512;
    const float* b1  = p[1] + l * 512;
    const float* wq  = p[2] + (size_t)l * 262144;
    const float* wk  = p[3] + (size_t)l * 262144;
    const float* wv  = p[4] + (size_t)l * 262144;
    const float* wo  = p[5] + (size_t)l * 262144;
    const float* wob = p[6] + l * 512;
    const float* g2  = p[7] + l * 512;
    const float* b2  = p[8] + l * 512;
    const float* f1W = p[9] + (size_t)l * 1048576;
    const float* f1b = p[10] + l * 2048;
    const float* f2W = p[11] + (size_t)l * 1048576;
    const float* f2b = p[12] + l * 512;

    // weight transpose+cast (bf16 [N][K])
    wtcast_k<<<dim3(16, 16), 256, 0, stream>>>(wq, 512, 512, wqkv_t);
    wtcast_k<<<dim3(16, 16), 256, 0, stream>>>(wk, 512, 512, wqkv_t + 262144);
    wtcast_k<<<dim3(16, 16), 256, 0, stream>>>(wv, 512, 512, wqkv_t + 524288);
    wtcast_k<<<dim3(16, 16), 256, 0, stream>>>(wo, 512, 512, wo_t);
    wtcast_k<<<dim3(64, 16), 256, 0, stream>>>(f1W, 512, 2048, f1_t);
    wtcast_k<<<dim3(16, 64), 256, 0, stream>>>(f2W, 2048, 512, f2_t);

    // ---- attention block ----
    cast_ln_k<<<32768, 256, 0, stream>>>(h, g1, b1, hn_bf);
    for (int r0 = 0; r0 < 32768; r0 += chunk_rows) {
        mgemm_k<0, 1, 0, 0><<<dim3(12, chunk_rows / 128), 256, 0, stream>>>(
            hn_bf + (size_t)r0 * 512, 512, wqkv_t, 512, nullptr,
            nullptr, nullptr, qkv, 1536, 512);
        attn2_k<<<(chunk_rows / 64) * 8, 256, 0, stream>>>(
            qkv, hn_bf + (size_t)r0 * 512);           // ctx overwrites hn_bf
    }
    mgemm_k<0, 0, 1, 1><<<dim3(4, 256), 256, 0, stream>>>(
        hn_bf, 512, wo_t, 512, wob, h, h, nullptr, 512, 512);

    // ---- FFN block ----
    cast_ln_k<<<32768, 256, 0, stream>>>(h, g2, b2, hn_bf);
    for (int c0 = 0; c0 < 2048; c0 += cw) {
        mgemm_k<1, 1, 0, 1><<<dim3(cw / 128, 256), 256, 0, stream>>>(
            hn_bf, 512, f1_t + (size_t)c0 * 512, 512, f1b + c0,
            nullptr, nullptr, f1c, cw, 512);
        if (c0 == 0)
            mgemm_k<0, 0, 1, 1><<<dim3(4, 256), 256, 0, stream>>>(
                f1c, cw, f2_t + c0, 2048, f2b, h, h, nullptr, 512, cw);
        else
            mgemm_k<0, 0, 1, 0><<<dim3(4, 256), 256, 0, stream>>>(
                f1c, cw, f2_t + c0, 2048, nullptr, h, h, nullptr, 512, cw);
    }
}

extern "C" void kernel_launch(void* const* d_in, const int* in_sizes, int n_in,
                              void* d_out, int out_size, void* d_ws, size_t ws_size,
                              hipStream_t stream)
{
    const float* x       = (const float*)d_in[0];
    const float* enc_inW = (const float*)d_in[1];
    const float* enc_inb = (const float*)d_in[2];
    const float* mu_W    = (const float*)d_in[3];
    const float* mu_b    = (const float*)d_in[4];
    const float* lv_W    = (const float*)d_in[5];
    const float* lv_b    = (const float*)d_in[6];
    const float* dec_inW = (const float*)d_in[7];
    const float* dec_inb = (const float*)d_in[8];
    const float* out_W   = (const float*)d_in[9];
    const float* out_b   = (const float*)d_in[10];
    const float* const* ep = (const float* const*)(d_in + 11);
    const float* const* dp = (const float* const*)(d_in + 26);

    float* fout   = (float*)d_out;             // recon (64,512,64)
    float* mu_out = fout + 2097152;            // (64,128)
    float* lv_out = mu_out + 8192;             // (64,128)

    const size_t SZ = (size_t)32768 * 512;
    size_t off = 0;
    char* base = (char*)d_ws;
    auto take = [&](size_t bytes) -> char* {
        char* pp = base + off;
        off = (off + bytes + 255) & ~(size_t)255;
        return pp;
    };
    float*          h      = (float*)take(SZ * 4);            // 64 MB
    unsigned short* hn_bf  = (unsigned short*)take(SZ * 2);   // 32 MB
    unsigned short* wqkv_t = (unsigned short*)take(1536 * 512 * 2);
    unsigned short* wo_t   = (unsigned short*)take(512 * 512 * 2);
    unsigned short* f1_t   = (unsigned short*)take(2048 * 512 * 2);
    unsigned short* f2_t   = (unsigned short*)take(512 * 2048 * 2);
    float*          stats  = (float*)take(65536 * 4);
    float*          pooled = (float*)take(131072);
    float*          zemb   = (float*)take(131072);

    // shared scratch: qkv (attention phase) / f1 chunk (FFN phase)
    unsigned short* qkv; unsigned short* f1c;
    int chunk_rows, cw;
    size_t rem = (ws_size > off) ? (ws_size - off) : 0;
    if (rem >= (size_t)32768 * 1536 * 2 + 512) {            // ~96.5 MB free
        qkv = (unsigned short*)take((size_t)32768 * 1536 * 2);
        chunk_rows = 32768; f1c = qkv; cw = 512;
    } else if (rem >= (size_t)32768 * 512 * 2 + 512) {      // ~33.6 MB free
        qkv = (unsigned short*)take((size_t)32768 * 512 * 2);
        chunk_rows = 8192;  f1c = qkv; cw = 512;            // 8192*1536*2 = 25.2MB
    } else {                                                 // ~12.6 MB free
        qkv = (unsigned short*)take((size_t)4096 * 1536 * 2);
        chunk_rows = 4096;
        f1c = (unsigned short*)fout; cw = 128;               // d_out recon = 8MB scratch
    }

    const int M = 32768;

    // ---------------- encoder ----------------
    embed_enc_k<<<M, 256, 0, stream>>>(x, enc_inW, enc_inb, h);
    for (int l = 0; l < 2; l++)
        run_layer2(ep, l, h, hn_bf, qkv, chunk_rows, f1c, cw,
                   wqkv_t, wo_t, f1_t, f2_t, stream);

    // ---------------- latent ----------------
    stats_k<<<M, 256, 0, stream>>>(h, stats);
    pool_ln_k<<<64, 512, 0, stream>>>(h, stats, ep[13], ep[14], pooled);
    gemm_k<0, 0, 0><<<dim3(2, 1), 256, 0, stream>>>(pooled, 512, mu_W, 128, mu_b,
                                                    nullptr, mu_out, 128, 512,
                                                    nullptr, nullptr, nullptr);
    gemm_k<0, 0, 0><<<dim3(2, 1), 256, 0, stream>>>(pooled, 512, lv_W, 128, lv_b,
                                                    nullptr, lv_out, 128, 512,
                                                    nullptr, nullptr, nullptr);
    gemm_k<0, 0, 0><<<dim3(8, 1), 256, 0, stream>>>(mu_out, 128, dec_inW, 512, dec_inb,
                                                    nullptr, zemb, 512, 128,
                                                    nullptr, nullptr, nullptr);
    dec_embed_k<<<65536, 256, 0, stream>>>(zemb, h);

    // ---------------- decoder ----------------
    for (int l = 0; l < 2; l++)
        run_layer2(dp, l, h, hn_bf, qkv, chunk_rows, f1c, cw,
                   wqkv_t, wo_t, f1_t, f2_t, stream);

    // final LN + out-proj, stored as (B,S,INP)
    stats_k<<<M, 256, 0, stream>>>(h, stats);
    gemm_k<0, 1, 1><<<dim3(1, M / 64), 256, 0, stream>>>(
        h, 512, out_W, 64, out_b, nullptr, fout, 64, 512, stats, dp[13], dp[14]);
}

// Round 4
// 2695.986 us; speedup vs baseline: 4.9743x; 1.3911x over previous
//
#include <hip/hip_runtime.h>
#include <math.h>

// TransformerVAE forward — round 3.
// Changes vs round 2: (1) embed as fp32 tile-GEMM + PE table, (2) vectorized
// dec_embed via PE table, (3) full-width FFN tier (single f1/f2 dispatches
// when workspace allows), (4) attn2 top-k/softmax parallelized across all
// 256 threads. No new quantization; absmax expected unchanged.
// B=64, S=512, INP=64, D=512, H=8, dk=64, L=2, DFF=2048, LAT=128, topk=6.
// Token layout: t = s*64 + b ((S,B,D) row-major). Attention across batch axis.

#define SQRT_D 22.62741699796952f
#define PE_C   0.017988946039015984f   // ln(10000)/512

typedef short frag8 __attribute__((ext_vector_type(8)));   // 8 bf16
typedef float accf4 __attribute__((ext_vector_type(4)));   // 4 fp32 acc

#define GLL16(g, l) __builtin_amdgcn_global_load_lds( \
    (const __attribute__((address_space(1))) void*)(g), \
    (__attribute__((address_space(3))) void*)(l), 16, 0, 0)

__device__ __forceinline__ float bf2f(unsigned short u) {
    union { unsigned i; float f; } v; v.i = ((unsigned)u) << 16; return v.f;
}
__device__ __forceinline__ unsigned short f2bf(float f) {   // RNE
    union { float f; unsigned i; } v; v.f = f;
    unsigned r = v.i + 0x7fff + ((v.i >> 16) & 1);
    return (unsigned short)(r >> 16);
}
__device__ __forceinline__ float pe_val(int s, int d) {
    float div = expf(-(float)(d & ~1) * PE_C);
    float ang = (float)s * div;
    return (d & 1) ? cosf(ang) : sinf(ang);
}
__device__ __forceinline__ float gelu_exact(float x) {
    return 0.5f * x * (1.0f + erff(x * 0.7071067811865476f));
}

// ---------------------------------------------------------------- PE table
__global__ __launch_bounds__(256) void pe_k(float* __restrict__ pe)
{
    const int s = blockIdx.x;
    const int d = threadIdx.x;
    pe[s * 512 + d]       = pe_val(s, d);
    pe[s * 512 + d + 256] = pe_val(s, d + 256);
}

// ---------------------------------------------------------------- embed (enc)
// h[(s*64+b), c] = (x[b,s,:] @ W + bias)[c] * sqrt(D) + PE[s,c]
// One block per (s, 64-col tile): 64x64 tile GEMM, K=64 fully resident.
__global__ __launch_bounds__(256) void embed_gemm_k(
    const float* __restrict__ x, const float* __restrict__ W,
    const float* __restrict__ bias, const float* __restrict__ pe,
    float* __restrict__ h)
{
    __shared__ float As[64][68];   // As[kk][b]
    __shared__ float Ws[64][68];   // Ws[kk][c]
    const int s = blockIdx.y;
    const int col0 = blockIdx.x * 64;
    const int tid = threadIdx.x;
#pragma unroll
    for (int i = 0; i < 16; i++) {
        int idx = i * 256 + tid;
        int r = idx >> 6, kk = idx & 63;         // lanes vary kk (coalesced)
        As[kk][r] = x[((size_t)r * 512 + s) * 64 + kk];       // r = b
        Ws[r][kk + (col0 & 0)] = 0.f;            // (no-op keeps symmetry)
        Ws[r][kk] = W[(size_t)r * 512 + col0 + kk];           // r = k, kk = c
    }
    __syncthreads();
    const int tm = (tid >> 4) << 2;
    const int tn = (tid & 15) << 2;
    float acc[4][4] = {};
#pragma unroll 8
    for (int kk = 0; kk < 64; kk++) {
        float4 a4 = *reinterpret_cast<const float4*>(&As[kk][tm]);
        float4 b4 = *reinterpret_cast<const float4*>(&Ws[kk][tn]);
        const float a[4] = {a4.x, a4.y, a4.z, a4.w};
        const float b[4] = {b4.x, b4.y, b4.z, b4.w};
#pragma unroll
        for (int i = 0; i < 4; i++)
#pragma unroll
            for (int j = 0; j < 4; j++)
                acc[i][j] += a[i] * b[j];
    }
    const int c = col0 + tn;
    float4 bi = *reinterpret_cast<const float4*>(&bias[c]);
    float4 pp = *reinterpret_cast<const float4*>(&pe[s * 512 + c]);
#pragma unroll
    for (int i = 0; i < 4; i++) {
        size_t row = ((size_t)s * 64 + tm + i) * 512;
        float4 o;
        o.x = (acc[i][0] + bi.x) * SQRT_D + pp.x;
        o.y = (acc[i][1] + bi.y) * SQRT_D + pp.y;
        o.z = (acc[i][2] + bi.z) * SQRT_D + pp.z;
        o.w = (acc[i][3] + bi.w) * SQRT_D + pp.w;
        *reinterpret_cast<float4*>(&h[row + c]) = o;
    }
}

// ---------------------------------------------------------------- embed (dec)
__global__ __launch_bounds__(256) void dec_embed_k(
    const float* __restrict__ zemb, const float* __restrict__ pe,
    float* __restrict__ h)
{
    const int i4 = (blockIdx.x * 256 + threadIdx.x) * 4;   // grid 16384
    const int d = i4 & 511;
    const int t = i4 >> 9;
    const int s = t >> 6, b = t & 63;
    float4 z = *reinterpret_cast<const float4*>(&zemb[b * 512 + d]);
    float4 p = *reinterpret_cast<const float4*>(&pe[s * 512 + d]);
    float4 o;
    o.x = z.x * SQRT_D + p.x;
    o.y = z.y * SQRT_D + p.y;
    o.z = z.z * SQRT_D + p.z;
    o.w = z.w * SQRT_D + p.w;
    *reinterpret_cast<float4*>(&h[i4]) = o;
}

// ---------------------------------------------------------------- LN stats
__global__ __launch_bounds__(256) void stats_k(
    const float* __restrict__ x, float* __restrict__ st)
{
    const int row = blockIdx.x;
    const int tid = threadIdx.x;
    const float* xr = x + (size_t)row * 512;
    float2 vv = *reinterpret_cast<const float2*>(&xr[tid * 2]);
    float v0 = vv.x, v1 = vv.y;
    float ssum = v0 + v1;
#pragma unroll
    for (int off = 32; off > 0; off >>= 1) ssum += __shfl_down(ssum, off, 64);
    __shared__ float red[4];
    __shared__ float red2[4];
    const int wid = tid >> 6, lane = tid & 63;
    if (lane == 0) red[wid] = ssum;
    __syncthreads();
    float m = (red[0] + red[1] + red[2] + red[3]) * (1.f / 512.f);
    float d0 = v0 - m, d1 = v1 - m;
    float s2 = d0 * d0 + d1 * d1;
#pragma unroll
    for (int off = 32; off > 0; off >>= 1) s2 += __shfl_down(s2, off, 64);
    if (lane == 0) red2[wid] = s2;
    __syncthreads();
    if (tid == 0) {
        float var = (red2[0] + red2[1] + red2[2] + red2[3]) * (1.f / 512.f);
        st[row * 2]     = m;
        st[row * 2 + 1] = rsqrtf(var + 1e-5f);
    }
}

// ---------------------------------------------------------------- LN -> bf16
__global__ __launch_bounds__(256) void cast_ln_k(
    const float* __restrict__ x, const float* __restrict__ g,
    const float* __restrict__ b, unsigned short* __restrict__ y)
{
    const int row = blockIdx.x;
    const int tid = threadIdx.x;
    const float* xr = x + (size_t)row * 512;
    float2 vv = *reinterpret_cast<const float2*>(&xr[tid * 2]);
    float v0 = vv.x, v1 = vv.y;
    float ssum = v0 + v1;
#pragma unroll
    for (int off = 32; off > 0; off >>= 1) ssum += __shfl_down(ssum, off, 64);
    __shared__ float red[4];
    __shared__ float red2[4];
    const int wid = tid >> 6, lane = tid & 63;
    if (lane == 0) red[wid] = ssum;
    __syncthreads();
    float m = (red[0] + red[1] + red[2] + red[3]) * (1.f / 512.f);
    float d0 = v0 - m, d1 = v1 - m;
    float s2 = d0 * d0 + d1 * d1;
#pragma unroll
    for (int off = 32; off > 0; off >>= 1) s2 += __shfl_down(s2, off, 64);
    if (lane == 0) red2[wid] = s2;
    __syncthreads();
    float var = (red2[0] + red2[1] + red2[2] + red2[3]) * (1.f / 512.f);
    float rstd = rsqrtf(var + 1e-5f);
    float2 gg = *reinterpret_cast<const float2*>(&g[tid * 2]);
    float2 bb = *reinterpret_cast<const float2*>(&b[tid * 2]);
    ushort2 o;
    o.x = f2bf(d0 * rstd * gg.x + bb.x);
    o.y = f2bf(d1 * rstd * gg.y + bb.y);
    *reinterpret_cast<ushort2*>(&y[(size_t)row * 512 + tid * 2]) = o;
}

// ------------------------------------------------------- weight transpose+cast
__global__ __launch_bounds__(256) void wtcast_k(
    const float* __restrict__ W, int Kd, int Nd, unsigned short* __restrict__ Wt)
{
    __shared__ float t[32][33];
    const int tx = threadIdx.x & 31, ty = threadIdx.x >> 5;   // ty 0..7
    const int n0 = blockIdx.x * 32, k0 = blockIdx.y * 32;
#pragma unroll
    for (int i = 0; i < 32; i += 8)
        t[ty + i][tx] = W[(size_t)(k0 + ty + i) * Nd + (n0 + tx)];
    __syncthreads();
#pragma unroll
    for (int i = 0; i < 32; i += 8)
        Wt[(size_t)(n0 + ty + i) * Kd + (k0 + tx)] = f2bf(t[tx][ty + i]);
}

// ---------------------------------------------------------------- MFMA GEMM
// C[M,N] = A[M,K](bf16) @ Bt[N,K](bf16)^T (+bias)(gelu?)(+fp32 res).
// 128x128 tile, BK=32, 256 threads = 4 waves (2x2), 4x4 16x16x32 MFMA / wave.
template<int ACT, int OUTBF, int RES, int BIAS>
__global__ __launch_bounds__(256) void mgemm_k(
    const unsigned short* __restrict__ A, int lda,
    const unsigned short* __restrict__ Bt, int ldb,
    const float* __restrict__ bias,
    const float* res, float* Cf, unsigned short* Cb, int ldc, int K)
{
    __shared__ unsigned short As[128 * 32];
    __shared__ unsigned short Bs[128 * 32];
    const int tid = threadIdx.x;
    const int wave = tid >> 6, lane = tid & 63;
    const int row0 = blockIdx.y * 128;
    const int col0 = blockIdx.x * 128;
    const int wr = wave >> 1, wc = wave & 1;
    accf4 acc[4][4] = {};
    const int srow = lane >> 2;
    const int scol = (lane & 3) * 8;
    const unsigned short* gA = A + (size_t)(row0 + srow) * lda + scol;
    const unsigned short* gB = Bt + (size_t)(col0 + srow) * ldb + scol;
    const int frow = lane & 15, fk = (lane >> 4) * 8;
    for (int k0 = 0; k0 < K; k0 += 32) {
#pragma unroll
        for (int r = 0; r < 2; r++) {
            int c = wave * 2 + r;
            GLL16(gA + (size_t)c * 16 * lda + k0, As + c * 512 + lane * 8);
            GLL16(gB + (size_t)c * 16 * ldb + k0, Bs + c * 512 + lane * 8);
        }
        __syncthreads();
        frag8 af[4], bfr[4];
#pragma unroll
        for (int i = 0; i < 4; i++)
            af[i] = *(const frag8*)&As[(wr * 64 + i * 16 + frow) * 32 + fk];
#pragma unroll
        for (int j = 0; j < 4; j++)
            bfr[j] = *(const frag8*)&Bs[(wc * 64 + j * 16 + frow) * 32 + fk];
#pragma unroll
        for (int i = 0; i < 4; i++)
#pragma unroll
            for (int j = 0; j < 4; j++)
                acc[i][j] = __builtin_amdgcn_mfma_f32_16x16x32_bf16(
                    af[i], bfr[j], acc[i][j], 0, 0, 0);
        __syncthreads();
    }
    const int lrow = (lane >> 4) * 4;
    const int lcol = lane & 15;
#pragma unroll
    for (int i = 0; i < 4; i++) {
#pragma unroll
        for (int reg = 0; reg < 4; reg++) {
            int r = row0 + wr * 64 + i * 16 + lrow + reg;
#pragma unroll
            for (int j = 0; j < 4; j++) {
                int c = col0 + wc * 64 + j * 16 + lcol;
                float v = acc[i][j][reg];
                if (BIAS) v += bias[c];
                if (ACT) v = gelu_exact(v);
                if (RES) v += res[(size_t)r * ldc + c];
                if (OUTBF) Cb[(size_t)r * ldc + c] = f2bf(v);
                else       Cf[(size_t)r * ldc + c] = v;
            }
        }
    }
}

// ---------------------------------------------------------------- attention
// One block per (s_local, head). Top-6/softmax parallel across all 256
// threads: row = tid&63, 16-col segment = tid>>6. Candidate/threshold
// storage lives in dead LDS (QT flat region + pad columns) — LDS stays 52KB.
__global__ __launch_bounds__(256) void attn2_k(
    const unsigned short* __restrict__ qkv, unsigned short* __restrict__ ctx)
{
    __shared__ float QT[64][68];   // Q^T [dim][row]; later P^T [col][row]
    __shared__ float KT[64][68];   // K^T [dim][col]; later scores^T [col][row]
    __shared__ float Vs[64][68];   // V [col][dim]; pad cols hold denom parts
    const int blk = blockIdx.x;
    const int sl = blk >> 3, hh = blk & 7;
    const int tid = threadIdx.x;
    const size_t qbase = (size_t)sl * 64 * 1536 + (size_t)hh * 64;
#pragma unroll
    for (int i = 0; i < 16; i++) {
        int idx = i * 256 + tid;
        int rr = idx >> 6, cc = idx & 63;
        const size_t g = qbase + (size_t)rr * 1536 + cc;
        QT[cc][rr] = bf2f(qkv[g]);
        KT[cc][rr] = bf2f(qkv[g + 512]);
        Vs[rr][cc] = bf2f(qkv[g + 1024]);
    }
    __syncthreads();
    const int tm = (tid >> 4) << 2;
    const int tn = (tid & 15) << 2;
    float sc[4][4] = {};
#pragma unroll 4
    for (int kk = 0; kk < 64; kk++) {
        float4 a4 = *reinterpret_cast<const float4*>(&QT[kk][tm]);
        float4 b4 = *reinterpret_cast<const float4*>(&KT[kk][tn]);
        const float a[4] = {a4.x, a4.y, a4.z, a4.w};
        const float b[4] = {b4.x, b4.y, b4.z, b4.w};
#pragma unroll
        for (int i = 0; i < 4; i++)
#pragma unroll
            for (int j = 0; j < 4; j++)
                sc[i][j] += a[i] * b[j];
    }
    __syncthreads();           // KT reads done; reuse as ScT
    float (*ScT)[68] = KT;     // scores^T [col][row]; [row][64]=thr,[row][65]=max
#pragma unroll
    for (int i = 0; i < 4; i++)
#pragma unroll
        for (int j = 0; j < 4; j++)
            ScT[tn + j][tm + i] = sc[i][j] * 0.125f;
    __syncthreads();
    // ---- top-6 + softmax, parallel over (row, seg) ----
    const int row = tid & 63, seg = tid >> 6;
    float* candp = &QT[0][0];           // QT dead until weights phase
    {
        float top[6];
#pragma unroll
        for (int i = 0; i < 6; i++) top[i] = -3.4e38f;
#pragma unroll
        for (int c = seg * 16; c < seg * 16 + 16; c++) {
            float vv = ScT[c][row];
            if (vv > top[5]) {
                top[5] = vv;
#pragma unroll
                for (int i = 5; i > 0; i--)
                    if (top[i] > top[i - 1]) { float t = top[i]; top[i] = top[i - 1]; top[i - 1] = t; }
            }
        }
#pragma unroll
        for (int i = 0; i < 6; i++) candp[row * 24 + seg * 6 + i] = top[i];
    }
    __syncthreads();
    if (seg == 0) {
        float t6[6];
#pragma unroll
        for (int i = 0; i < 6; i++) t6[i] = -3.4e38f;
#pragma unroll
        for (int j = 0; j < 24; j++) {
            float vv = candp[row * 24 + j];
            if (vv > t6[5]) {
                t6[5] = vv;
#pragma unroll
                for (int i = 5; i > 0; i--)
                    if (t6[i] > t6[i - 1]) { float t = t6[i]; t6[i] = t6[i - 1]; t6[i - 1] = t; }
            }
        }
        ScT[row][64] = t6[5];   // threshold (6th largest; ties kept via >=)
        ScT[row][65] = t6[0];   // row max
    }
    __syncthreads();
    {
        const float thresh = ScT[row][64], mx = ScT[row][65];
        float dsum = 0.f;
#pragma unroll
        for (int c = seg * 16; c < seg * 16 + 16; c++) {
            float vv = ScT[c][row];
            float w = (vv >= thresh) ? expf(vv - mx) : 0.f;
            dsum += w;
            QT[c][row] = w;     // P^T
        }
        Vs[row][64 + seg] = dsum;
    }
    __syncthreads();
    {
        const float rd = 1.f / (Vs[row][64] + Vs[row][65] + Vs[row][66] + Vs[row][67]);
#pragma unroll
        for (int c = seg * 16; c < seg * 16 + 16; c++) QT[c][row] *= rd;
    }
    __syncthreads();
    {   // ctx[r][j] = sum_c P[r][c] * V[c][j]
        float acc[4][4] = {};
#pragma unroll 4
        for (int c = 0; c < 64; c++) {
            float4 p4 = *reinterpret_cast<const float4*>(&QT[c][tm]);
            float4 v4 = *reinterpret_cast<const float4*>(&Vs[c][tn]);
            const float p[4] = {p4.x, p4.y, p4.z, p4.w};
            const float b[4] = {v4.x, v4.y, v4.z, v4.w};
#pragma unroll
            for (int i = 0; i < 4; i++)
#pragma unroll
                for (int j = 0; j < 4; j++)
                    acc[i][j] += p[i] * b[j];
        }
#pragma unroll
        for (int i = 0; i < 4; i++) {
            ushort4 o;
            o.x = f2bf(acc[i][0]); o.y = f2bf(acc[i][1]);
            o.z = f2bf(acc[i][2]); o.w = f2bf(acc[i][3]);
            *reinterpret_cast<ushort4*>(
                &ctx[(size_t)(sl * 64 + tm + i) * 512 + hh * 64 + tn]) = o;
        }
    }
}

// ---------------------------------------------------------- fp32 GEMM (small)
template<int ACT, int PERM, int LN>
__global__ __launch_bounds__(256) void gemm_k(
    const float* __restrict__ A, int lda,
    const float* __restrict__ W, int ldw,
    const float* __restrict__ bias,
    const float* res,
    float* C, int ldc,
    int K,
    const float* __restrict__ stats,
    const float* __restrict__ lng, const float* __restrict__ lnb)
{
    __shared__ float As[16][68];
    __shared__ float Ws[16][68];
    __shared__ float ms[64], rss[64];
    const int row0 = blockIdx.y * 64;
    const int col0 = blockIdx.x * 64;
    const int tid = threadIdx.x;
    if (LN) {
        if (tid < 64) {
            ms[tid]  = stats[(row0 + tid) * 2];
            rss[tid] = stats[(row0 + tid) * 2 + 1];
        }
        __syncthreads();
    }
    const int tm = (tid >> 4) << 2;
    const int tn = (tid & 15) << 2;
    float acc[4][4] = {};
    for (int k0 = 0; k0 < K; k0 += 16) {
#pragma unroll
        for (int i = 0; i < 4; i++) {
            int idx = i * 256 + tid;
            int r = idx >> 4, kk = idx & 15;
            float v = A[(size_t)(row0 + r) * lda + (k0 + kk)];
            if (LN) v = (v - ms[r]) * rss[r] * lng[k0 + kk] + lnb[k0 + kk];
            As[kk][r] = v;
        }
#pragma unroll
        for (int i = 0; i < 4; i++) {
            int idx = i * 256 + tid;
            int kk = idx >> 6, c = idx & 63;
            Ws[kk][c] = W[(size_t)(k0 + kk) * ldw + (col0 + c)];
        }
        __syncthreads();
#pragma unroll
        for (int kk = 0; kk < 16; kk++) {
            float4 a4 = *reinterpret_cast<const float4*>(&As[kk][tm]);
            float4 b4 = *reinterpret_cast<const float4*>(&Ws[kk][tn]);
            const float a[4] = {a4.x, a4.y, a4.z, a4.w};
            const float b[4] = {b4.x, b4.y, b4.z, b4.w};
#pragma unroll
            for (int i = 0; i < 4; i++)
#pragma unroll
                for (int j = 0; j < 4; j++)
                    acc[i][j] += a[i] * b[j];
        }
        __syncthreads();
    }
#pragma unroll
    for (int i = 0; i < 4; i++) {
        int r = row0 + tm + i;
#pragma unroll
        for (int j = 0; j < 4; j++) {
            int c = col0 + tn + j;
            float v = acc[i][j];
            if (bias) v += bias[c];
            if (ACT == 1) v = gelu_exact(v);
            if (res) v += res[(size_t)r * ldc + c];
            if (PERM) {
                int bb = r & 63, ss = r >> 6;
                C[((size_t)bb * 512 + ss) * ldc + c] = v;
            } else {
                C[(size_t)r * ldc + c] = v;
            }
        }
    }
}

// ---------------------------------------------------------------- pool (+LN)
__global__ __launch_bounds__(512) void pool_ln_k(
    const float* __restrict__ h, const float* __restrict__ st,
    const float* __restrict__ gf, const float* __restrict__ bf,
    float* __restrict__ pooled)
{
    const int b = blockIdx.x;
    const int d = threadIdx.x;
    const float g = gf[d], bb = bf[d];
    float acc = 0.f;
    for (int s = 0; s < 512; s++) {
        int r = s * 64 + b;
        float m = st[r * 2], rs = st[r * 2 + 1];
        acc += (h[(size_t)r * 512 + d] - m) * rs * g + bb;
    }
    pooled[b * 512 + d] = acc * (1.f / 512.f);
}

// ---------------------------------------------------------------- host side
static void run_layer2(const float* const* p, int l,
                       float* h, unsigned short* hn_bf,
                       unsigned short* qkv, int chunk_rows,
                       unsigned short* f1c, int cw,
                       unsigned short* wqkv_t, unsigned short* wo_t,
                       unsigned short* f1_t, unsigned short* f2_t,
                       hipStream_t stream)
{
    const float* g1  = p[0] + l * 512;
    const float* b1  = p[1] + l * 512;
    const float* wq  = p[2] + (size_t)l * 262144;
    const float* wk  = p[3] + (size_t)l * 262144;
    const float* wv  = p[4] + (size_t)l * 262144;
    const float* wo  = p[5] + (size_t)l * 262144;
    const float* wob = p[6] + l * 512;
    const float* g2  = p[7] + l * 512;
    const float* b2  = p[8] + l * 512;
    const float* f1W = p[9] + (size_t)l * 1048576;
    const float* f1b = p[10] + l * 2048;
    const float* f2W = p[11] + (size_t)l * 1048576;
    const float* f2b = p[12] + l * 512;

    // weight transpose+cast (bf16 [N][K])
    wtcast_k<<<dim3(16, 16), 256, 0, stream>>>(wq, 512, 512, wqkv_t);
    wtcast_k<<<dim3(16, 16), 256, 0, stream>>>(wk, 512, 512, wqkv_t + 262144);
    wtcast_k<<<dim3(16, 16), 256, 0, stream>>>(wv, 512, 512, wqkv_t + 524288);
    wtcast_k<<<dim3(16, 16), 256, 0, stream>>>(wo, 512, 512, wo_t);
    wtcast_k<<<dim3(64, 16), 256, 0, stream>>>(f1W, 512, 2048, f1_t);
    wtcast_k<<<dim3(16, 64), 256, 0, stream>>>(f2W, 2048, 512, f2_t);

    // ---- attention block ----
    cast_ln_k<<<32768, 256, 0, stream>>>(h, g1, b1, hn_bf);
    for (int r0 = 0; r0 < 32768; r0 += chunk_rows) {
        mgemm_k<0, 1, 0, 0><<<dim3(12, chunk_rows / 128), 256, 0, stream>>>(
            hn_bf + (size_t)r0 * 512, 512, wqkv_t, 512, nullptr,
            nullptr, nullptr, qkv, 1536, 512);
        attn2_k<<<(chunk_rows / 64) * 8, 256, 0, stream>>>(
            qkv, hn_bf + (size_t)r0 * 512);           // ctx overwrites hn_bf
    }
    mgemm_k<0, 0, 1, 1><<<dim3(4, 256), 256, 0, stream>>>(
        hn_bf, 512, wo_t, 512, wob, h, h, nullptr, 512, 512);

    // ---- FFN block ----
    cast_ln_k<<<32768, 256, 0, stream>>>(h, g2, b2, hn_bf);
    for (int c0 = 0; c0 < 2048; c0 += cw) {
        mgemm_k<1, 1, 0, 1><<<dim3(cw / 128, 256), 256, 0, stream>>>(
            hn_bf, 512, f1_t + (size_t)c0 * 512, 512, f1b + c0,
            nullptr, nullptr, f1c, cw, 512);
        if (c0 == 0)
            mgemm_k<0, 0, 1, 1><<<dim3(4, 256), 256, 0, stream>>>(
                f1c, cw, f2_t + c0, 2048, f2b, h, h, nullptr, 512, cw);
        else
            mgemm_k<0, 0, 1, 0><<<dim3(4, 256), 256, 0, stream>>>(
                f1c, cw, f2_t + c0, 2048, nullptr, h, h, nullptr, 512, cw);
    }
}

extern "C" void kernel_launch(void* const* d_in, const int* in_sizes, int n_in,
                              void* d_out, int out_size, void* d_ws, size_t ws_size,
                              hipStream_t stream)
{
    const float* x       = (const float*)d_in[0];
    const float* enc_inW = (const float*)d_in[1];
    const float* enc_inb = (const float*)d_in[2];
    const float* mu_W    = (const float*)d_in[3];
    const float* mu_b    = (const float*)d_in[4];
    const float* lv_W    = (const float*)d_in[5];
    const float* lv_b    = (const float*)d_in[6];
    const float* dec_inW = (const float*)d_in[7];
    const float* dec_inb = (const float*)d_in[8];
    const float* out_W   = (const float*)d_in[9];
    const float* out_b   = (const float*)d_in[10];
    const float* const* ep = (const float* const*)(d_in + 11);
    const float* const* dp = (const float* const*)(d_in + 26);

    float* fout   = (float*)d_out;             // recon (64,512,64)
    float* mu_out = fout + 2097152;            // (64,128)
    float* lv_out = mu_out + 8192;             // (64,128)

    const size_t SZ = (size_t)32768 * 512;
    size_t off = 0;
    char* base = (char*)d_ws;
    auto take = [&](size_t bytes) -> char* {
        char* pp = base + off;
        off = (off + bytes + 255) & ~(size_t)255;
        return pp;
    };
    float*          h      = (float*)take(SZ * 4);            // 64 MB
    unsigned short* hn_bf  = (unsigned short*)take(SZ * 2);   // 32 MB
    unsigned short* wqkv_t = (unsigned short*)take(1536 * 512 * 2);
    unsigned short* wo_t   = (unsigned short*)take(512 * 512 * 2);
    unsigned short* f1_t   = (unsigned short*)take(2048 * 512 * 2);
    unsigned short* f2_t   = (unsigned short*)take(512 * 2048 * 2);
    float*          stats  = (float*)take(65536 * 4);
    float*          pooled = (float*)take(131072);
    float*          zemb   = (float*)take(131072);
    float*          pe     = (float*)take(512 * 512 * 4);     // 1 MB

    // shared scratch: qkv (attention phase) / f1 chunk (FFN phase)
    unsigned short* qkv; unsigned short* f1c;
    int chunk_rows, cw;
    size_t rem = (ws_size > off) ? (ws_size - off) : 0;
    const size_t F1_FULL  = (size_t)32768 * 2048 * 2;   // 128 MB
    const size_t QKV_FULL = (size_t)32768 * 1536 * 2;   // 96 MB
    if (rem >= F1_FULL + 512) {                 // single-dispatch FFN tier
        unsigned short* share = (unsigned short*)take(F1_FULL);
        qkv = share; f1c = share; chunk_rows = 32768; cw = 2048;
    } else if (rem >= QKV_FULL + 512) {
        unsigned short* share = (unsigned short*)take(QKV_FULL);
        qkv = share; f1c = share; chunk_rows = 32768; cw = 512;
    } else if (rem >= (size_t)32768 * 512 * 2 + 512) {
        unsigned short* share = (unsigned short*)take((size_t)32768 * 512 * 2);
        qkv = share; f1c = share; chunk_rows = 8192; cw = 512;
    } else {
        qkv = (unsigned short*)take((size_t)4096 * 1536 * 2);
        chunk_rows = 4096;
        f1c = (unsigned short*)fout; cw = 128;  // d_out recon = 8MB scratch
    }

    const int M = 32768;

    pe_k<<<512, 256, 0, stream>>>(pe);

    // ---------------- encoder ----------------
    embed_gemm_k<<<dim3(8, 512), 256, 0, stream>>>(x, enc_inW, enc_inb, pe, h);
    for (int l = 0; l < 2; l++)
        run_layer2(ep, l, h, hn_bf, qkv, chunk_rows, f1c, cw,
                   wqkv_t, wo_t, f1_t, f2_t, stream);

    // ---------------- latent ----------------
    stats_k<<<M, 256, 0, stream>>>(h, stats);
    pool_ln_k<<<64, 512, 0, stream>>>(h, stats, ep[13], ep[14], pooled);
    gemm_k<0, 0, 0><<<dim3(2, 1), 256, 0, stream>>>(pooled, 512, mu_W, 128, mu_b,
                                                    nullptr, mu_out, 128, 512,
                                                    nullptr, nullptr, nullptr);
    gemm_k<0, 0, 0><<<dim3(2, 1), 256, 0, stream>>>(pooled, 512, lv_W, 128, lv_b,
                                                    nullptr, lv_out, 128, 512,
                                                    nullptr, nullptr, nullptr);
    gemm_k<0, 0, 0><<<dim3(8, 1), 256, 0, stream>>>(mu_out, 128, dec_inW, 512, dec_inb,
                                                    nullptr, zemb, 512, 128,
                                                    nullptr, nullptr, nullptr);
    dec_embed_k<<<16384, 256, 0, stream>>>(zemb, pe, h);

    // ---------------- decoder ----------------
    for (int l = 0; l < 2; l++)
        run_layer2(dp, l, h, hn_bf, qkv, chunk_rows, f1c, cw,
                   wqkv_t, wo_t, f1_t, f2_t, stream);

    // final LN + out-proj, stored as (B,S,INP)
    stats_k<<<M, 256, 0, stream>>>(h, stats);
    gemm_k<0, 1, 1><<<dim3(1, M / 64), 256, 0, stream>>>(
        h, 512, out_W, 64, out_b, nullptr, fout, 64, 512, stats, dp[13], dp[14]);
}

// Round 5
// 2559.070 us; speedup vs baseline: 5.2404x; 1.0535x over previous
//
#include <hip/hip_runtime.h>
#include <math.h>

// TransformerVAE forward — round 4.
// Changes vs round 3:
//  (a) mgemm grid transposed (blockIdx.x = row tile): the 4..16 blocks that
//      share an A row-strip now have linear ids differing by multiples of
//      256 (≡0 mod 8) -> same XCD -> A fetched once into that XCD's L2.
//  (b) MFMA operand swap: mfma(bfr, af, acc) computes the transposed tile so
//      accumulator regs advance along C columns -> fully vectorized float4 /
//      ushort4 epilogue (bias, gelu, residual, store).
//  (c) per-layer weight transposes batched into one z-indexed dispatch.
// B=64, S=512, INP=64, D=512, H=8, dk=64, L=2, DFF=2048, LAT=128, topk=6.
// Token layout: t = s*64 + b ((S,B,D) row-major). Attention across batch axis.

#define SQRT_D 22.62741699796952f
#define PE_C   0.017988946039015984f   // ln(10000)/512

typedef short frag8 __attribute__((ext_vector_type(8)));   // 8 bf16
typedef float accf4 __attribute__((ext_vector_type(4)));   // 4 fp32 acc

#define GLL16(g, l) __builtin_amdgcn_global_load_lds( \
    (const __attribute__((address_space(1))) void*)(g), \
    (__attribute__((address_space(3))) void*)(l), 16, 0, 0)

__device__ __forceinline__ float bf2f(unsigned short u) {
    union { unsigned i; float f; } v; v.i = ((unsigned)u) << 16; return v.f;
}
__device__ __forceinline__ unsigned short f2bf(float f) {   // RNE
    union { float f; unsigned i; } v; v.f = f;
    unsigned r = v.i + 0x7fff + ((v.i >> 16) & 1);
    return (unsigned short)(r >> 16);
}
__device__ __forceinline__ float pe_val(int s, int d) {
    float div = expf(-(float)(d & ~1) * PE_C);
    float ang = (float)s * div;
    return (d & 1) ? cosf(ang) : sinf(ang);
}
__device__ __forceinline__ float gelu_exact(float x) {
    return 0.5f * x * (1.0f + erff(x * 0.7071067811865476f));
}

// ---------------------------------------------------------------- PE table
__global__ __launch_bounds__(256) void pe_k(float* __restrict__ pe)
{
    const int s = blockIdx.x;
    const int d = threadIdx.x;
    pe[s * 512 + d]       = pe_val(s, d);
    pe[s * 512 + d + 256] = pe_val(s, d + 256);
}

// ---------------------------------------------------------------- embed (enc)
__global__ __launch_bounds__(256) void embed_gemm_k(
    const float* __restrict__ x, const float* __restrict__ W,
    const float* __restrict__ bias, const float* __restrict__ pe,
    float* __restrict__ h)
{
    __shared__ float As[64][68];   // As[kk][b]
    __shared__ float Ws[64][68];   // Ws[kk][c]
    const int s = blockIdx.y;
    const int col0 = blockIdx.x * 64;
    const int tid = threadIdx.x;
#pragma unroll
    for (int i = 0; i < 16; i++) {
        int idx = i * 256 + tid;
        int r = idx >> 6, kk = idx & 63;
        As[kk][r] = x[((size_t)r * 512 + s) * 64 + kk];       // r = b
        Ws[r][kk] = W[(size_t)r * 512 + col0 + kk];           // r = k, kk = c
    }
    __syncthreads();
    const int tm = (tid >> 4) << 2;
    const int tn = (tid & 15) << 2;
    float acc[4][4] = {};
#pragma unroll 8
    for (int kk = 0; kk < 64; kk++) {
        float4 a4 = *reinterpret_cast<const float4*>(&As[kk][tm]);
        float4 b4 = *reinterpret_cast<const float4*>(&Ws[kk][tn]);
        const float a[4] = {a4.x, a4.y, a4.z, a4.w};
        const float b[4] = {b4.x, b4.y, b4.z, b4.w};
#pragma unroll
        for (int i = 0; i < 4; i++)
#pragma unroll
            for (int j = 0; j < 4; j++)
                acc[i][j] += a[i] * b[j];
    }
    const int c = col0 + tn;
    float4 bi = *reinterpret_cast<const float4*>(&bias[c]);
    float4 pp = *reinterpret_cast<const float4*>(&pe[s * 512 + c]);
#pragma unroll
    for (int i = 0; i < 4; i++) {
        size_t row = ((size_t)s * 64 + tm + i) * 512;
        float4 o;
        o.x = (acc[i][0] + bi.x) * SQRT_D + pp.x;
        o.y = (acc[i][1] + bi.y) * SQRT_D + pp.y;
        o.z = (acc[i][2] + bi.z) * SQRT_D + pp.z;
        o.w = (acc[i][3] + bi.w) * SQRT_D + pp.w;
        *reinterpret_cast<float4*>(&h[row + c]) = o;
    }
}

// ---------------------------------------------------------------- embed (dec)
__global__ __launch_bounds__(256) void dec_embed_k(
    const float* __restrict__ zemb, const float* __restrict__ pe,
    float* __restrict__ h)
{
    const int i4 = (blockIdx.x * 256 + threadIdx.x) * 4;   // grid 16384
    const int d = i4 & 511;
    const int t = i4 >> 9;
    const int s = t >> 6, b = t & 63;
    float4 z = *reinterpret_cast<const float4*>(&zemb[b * 512 + d]);
    float4 p = *reinterpret_cast<const float4*>(&pe[s * 512 + d]);
    float4 o;
    o.x = z.x * SQRT_D + p.x;
    o.y = z.y * SQRT_D + p.y;
    o.z = z.z * SQRT_D + p.z;
    o.w = z.w * SQRT_D + p.w;
    *reinterpret_cast<float4*>(&h[i4]) = o;
}

// ---------------------------------------------------------------- LN stats
__global__ __launch_bounds__(256) void stats_k(
    const float* __restrict__ x, float* __restrict__ st)
{
    const int row = blockIdx.x;
    const int tid = threadIdx.x;
    const float* xr = x + (size_t)row * 512;
    float2 vv = *reinterpret_cast<const float2*>(&xr[tid * 2]);
    float v0 = vv.x, v1 = vv.y;
    float ssum = v0 + v1;
#pragma unroll
    for (int off = 32; off > 0; off >>= 1) ssum += __shfl_down(ssum, off, 64);
    __shared__ float red[4];
    __shared__ float red2[4];
    const int wid = tid >> 6, lane = tid & 63;
    if (lane == 0) red[wid] = ssum;
    __syncthreads();
    float m = (red[0] + red[1] + red[2] + red[3]) * (1.f / 512.f);
    float d0 = v0 - m, d1 = v1 - m;
    float s2 = d0 * d0 + d1 * d1;
#pragma unroll
    for (int off = 32; off > 0; off >>= 1) s2 += __shfl_down(s2, off, 64);
    if (lane == 0) red2[wid] = s2;
    __syncthreads();
    if (tid == 0) {
        float var = (red2[0] + red2[1] + red2[2] + red2[3]) * (1.f / 512.f);
        st[row * 2]     = m;
        st[row * 2 + 1] = rsqrtf(var + 1e-5f);
    }
}

// ---------------------------------------------------------------- LN -> bf16
__global__ __launch_bounds__(256) void cast_ln_k(
    const float* __restrict__ x, const float* __restrict__ g,
    const float* __restrict__ b, unsigned short* __restrict__ y)
{
    const int row = blockIdx.x;
    const int tid = threadIdx.x;
    const float* xr = x + (size_t)row * 512;
    float2 vv = *reinterpret_cast<const float2*>(&xr[tid * 2]);
    float v0 = vv.x, v1 = vv.y;
    float ssum = v0 + v1;
#pragma unroll
    for (int off = 32; off > 0; off >>= 1) ssum += __shfl_down(ssum, off, 64);
    __shared__ float red[4];
    __shared__ float red2[4];
    const int wid = tid >> 6, lane = tid & 63;
    if (lane == 0) red[wid] = ssum;
    __syncthreads();
    float m = (red[0] + red[1] + red[2] + red[3]) * (1.f / 512.f);
    float d0 = v0 - m, d1 = v1 - m;
    float s2 = d0 * d0 + d1 * d1;
#pragma unroll
    for (int off = 32; off > 0; off >>= 1) s2 += __shfl_down(s2, off, 64);
    if (lane == 0) red2[wid] = s2;
    __syncthreads();
    float var = (red2[0] + red2[1] + red2[2] + red2[3]) * (1.f / 512.f);
    float rstd = rsqrtf(var + 1e-5f);
    float2 gg = *reinterpret_cast<const float2*>(&g[tid * 2]);
    float2 bb = *reinterpret_cast<const float2*>(&b[tid * 2]);
    ushort2 o;
    o.x = f2bf(d0 * rstd * gg.x + bb.x);
    o.y = f2bf(d1 * rstd * gg.y + bb.y);
    *reinterpret_cast<ushort2*>(&y[(size_t)row * 512 + tid * 2]) = o;
}

// ------------------------------------------------------- weight transpose+cast
// Six W[Kd][Nd] fp32 -> Wt[Nd][Kd] bf16 transposes in one dispatch (z = which).
struct WTDesc { const float* src; unsigned short* dst; int Kd; int Nd; };

__global__ __launch_bounds__(256) void wtcast6_k(
    WTDesc d0, WTDesc d1, WTDesc d2, WTDesc d3, WTDesc d4, WTDesc d5)
{
    WTDesc d;
    switch (blockIdx.z) {
        case 0: d = d0; break; case 1: d = d1; break; case 2: d = d2; break;
        case 3: d = d3; break; case 4: d = d4; break; default: d = d5; break;
    }
    const int n0 = blockIdx.x * 32, k0 = blockIdx.y * 32;
    if (n0 >= d.Nd || k0 >= d.Kd) return;
    __shared__ float t[32][33];
    const int tx = threadIdx.x & 31, ty = threadIdx.x >> 5;   // ty 0..7
#pragma unroll
    for (int i = 0; i < 32; i += 8)
        t[ty + i][tx] = d.src[(size_t)(k0 + ty + i) * d.Nd + (n0 + tx)];
    __syncthreads();
#pragma unroll
    for (int i = 0; i < 32; i += 8)
        d.dst[(size_t)(n0 + ty + i) * d.Kd + (k0 + tx)] = f2bf(t[tx][ty + i]);
}

// ---------------------------------------------------------------- MFMA GEMM
// C[M,N] = A[M,K](bf16) @ Bt[N,K](bf16)^T (+bias)(gelu?)(+fp32 res).
// 128x128 tile, BK=32, 256 threads = 4 waves (2x2), 4x4 16x16x32 MFMA / wave.
// blockIdx.x = ROW tile (so same-A blocks share an XCD), blockIdx.y = col.
// Operand-swapped MFMA: acc regs advance along C columns -> float4 epilogue.
template<int ACT, int OUTBF, int RES, int BIAS>
__global__ __launch_bounds__(256) void mgemm_k(
    const unsigned short* __restrict__ A, int lda,
    const unsigned short* __restrict__ Bt, int ldb,
    const float* __restrict__ bias,
    const float* res, float* Cf, unsigned short* Cb, int ldc, int K)
{
    __shared__ unsigned short As[128 * 32];
    __shared__ unsigned short Bs[128 * 32];
    const int tid = threadIdx.x;
    const int wave = tid >> 6, lane = tid & 63;
    const int row0 = blockIdx.x * 128;
    const int col0 = blockIdx.y * 128;
    const int wr = wave >> 1, wc = wave & 1;
    accf4 acc[4][4] = {};
    const int srow = lane >> 2;
    const int scol = (lane & 3) * 8;
    const unsigned short* gA = A + (size_t)(row0 + srow) * lda + scol;
    const unsigned short* gB = Bt + (size_t)(col0 + srow) * ldb + scol;
    const int frow = lane & 15, fk = (lane >> 4) * 8;
    for (int k0 = 0; k0 < K; k0 += 32) {
#pragma unroll
        for (int r = 0; r < 2; r++) {
            int c = wave * 2 + r;
            GLL16(gA + (size_t)c * 16 * lda + k0, As + c * 512 + lane * 8);
            GLL16(gB + (size_t)c * 16 * ldb + k0, Bs + c * 512 + lane * 8);
        }
        __syncthreads();
        frag8 af[4], bfr[4];
#pragma unroll
        for (int i = 0; i < 4; i++)
            af[i] = *(const frag8*)&As[(wr * 64 + i * 16 + frow) * 32 + fk];
#pragma unroll
        for (int j = 0; j < 4; j++)
            bfr[j] = *(const frag8*)&Bs[(wc * 64 + j * 16 + frow) * 32 + fk];
#pragma unroll
        for (int i = 0; i < 4; i++)
#pragma unroll
            for (int j = 0; j < 4; j++)
                acc[i][j] = __builtin_amdgcn_mfma_f32_16x16x32_bf16(
                    bfr[j], af[i], acc[i][j], 0, 0, 0);   // swapped: D = C^T tile
        __syncthreads();
    }
    // Swapped C/D mapping: row_C = lane&15, col_C = (lane>>4)*4 + reg.
    const int lrow = lane & 15;
    const int lcol = (lane >> 4) * 4;
#pragma unroll
    for (int i = 0; i < 4; i++) {
        const int r = row0 + wr * 64 + i * 16 + lrow;
#pragma unroll
        for (int j = 0; j < 4; j++) {
            const int c = col0 + wc * 64 + j * 16 + lcol;
            float4 v = make_float4(acc[i][j][0], acc[i][j][1],
                                   acc[i][j][2], acc[i][j][3]);
            if (BIAS) {
                float4 bi = *reinterpret_cast<const float4*>(&bias[c]);
                v.x += bi.x; v.y += bi.y; v.z += bi.z; v.w += bi.w;
            }
            if (ACT) {
                v.x = gelu_exact(v.x); v.y = gelu_exact(v.y);
                v.z = gelu_exact(v.z); v.w = gelu_exact(v.w);
            }
            if (RES) {
                float4 rr = *reinterpret_cast<const float4*>(&res[(size_t)r * ldc + c]);
                v.x += rr.x; v.y += rr.y; v.z += rr.z; v.w += rr.w;
            }
            if (OUTBF) {
                ushort4 o;
                o.x = f2bf(v.x); o.y = f2bf(v.y); o.z = f2bf(v.z); o.w = f2bf(v.w);
                *reinterpret_cast<ushort4*>(&Cb[(size_t)r * ldc + c]) = o;
            } else {
                *reinterpret_cast<float4*>(&Cf[(size_t)r * ldc + c]) = v;
            }
        }
    }
}

// ---------------------------------------------------------------- attention
__global__ __launch_bounds__(256) void attn2_k(
    const unsigned short* __restrict__ qkv, unsigned short* __restrict__ ctx)
{
    __shared__ float QT[64][68];   // Q^T [dim][row]; later P^T [col][row]
    __shared__ float KT[64][68];   // K^T [dim][col]; later scores^T [col][row]
    __shared__ float Vs[64][68];   // V [col][dim]; pad cols hold denom parts
    const int blk = blockIdx.x;
    const int sl = blk >> 3, hh = blk & 7;
    const int tid = threadIdx.x;
    const size_t qbase = (size_t)sl * 64 * 1536 + (size_t)hh * 64;
#pragma unroll
    for (int i = 0; i < 16; i++) {
        int idx = i * 256 + tid;
        int rr = idx >> 6, cc = idx & 63;
        const size_t g = qbase + (size_t)rr * 1536 + cc;
        QT[cc][rr] = bf2f(qkv[g]);
        KT[cc][rr] = bf2f(qkv[g + 512]);
        Vs[rr][cc] = bf2f(qkv[g + 1024]);
    }
    __syncthreads();
    const int tm = (tid >> 4) << 2;
    const int tn = (tid & 15) << 2;
    float sc[4][4] = {};
#pragma unroll 4
    for (int kk = 0; kk < 64; kk++) {
        float4 a4 = *reinterpret_cast<const float4*>(&QT[kk][tm]);
        float4 b4 = *reinterpret_cast<const float4*>(&KT[kk][tn]);
        const float a[4] = {a4.x, a4.y, a4.z, a4.w};
        const float b[4] = {b4.x, b4.y, b4.z, b4.w};
#pragma unroll
        for (int i = 0; i < 4; i++)
#pragma unroll
            for (int j = 0; j < 4; j++)
                sc[i][j] += a[i] * b[j];
    }
    __syncthreads();           // KT reads done; reuse as ScT
    float (*ScT)[68] = KT;     // scores^T [col][row]; [row][64]=thr,[row][65]=max
#pragma unroll
    for (int i = 0; i < 4; i++)
#pragma unroll
        for (int j = 0; j < 4; j++)
            ScT[tn + j][tm + i] = sc[i][j] * 0.125f;
    __syncthreads();
    // ---- top-6 + softmax, parallel over (row, seg) ----
    const int row = tid & 63, seg = tid >> 6;
    float* candp = &QT[0][0];           // QT dead until weights phase
    {
        float top[6];
#pragma unroll
        for (int i = 0; i < 6; i++) top[i] = -3.4e38f;
#pragma unroll
        for (int c = seg * 16; c < seg * 16 + 16; c++) {
            float vv = ScT[c][row];
            if (vv > top[5]) {
                top[5] = vv;
#pragma unroll
                for (int i = 5; i > 0; i--)
                    if (top[i] > top[i - 1]) { float t = top[i]; top[i] = top[i - 1]; top[i - 1] = t; }
            }
        }
#pragma unroll
        for (int i = 0; i < 6; i++) candp[row * 24 + seg * 6 + i] = top[i];
    }
    __syncthreads();
    if (seg == 0) {
        float t6[6];
#pragma unroll
        for (int i = 0; i < 6; i++) t6[i] = -3.4e38f;
#pragma unroll
        for (int j = 0; j < 24; j++) {
            float vv = candp[row * 24 + j];
            if (vv > t6[5]) {
                t6[5] = vv;
#pragma unroll
                for (int i = 5; i > 0; i--)
                    if (t6[i] > t6[i - 1]) { float t = t6[i]; t6[i] = t6[i - 1]; t6[i - 1] = t; }
            }
        }
        ScT[row][64] = t6[5];   // threshold (6th largest; ties kept via >=)
        ScT[row][65] = t6[0];   // row max
    }
    __syncthreads();
    {
        const float thresh = ScT[row][64], mx = ScT[row][65];
        float dsum = 0.f;
#pragma unroll
        for (int c = seg * 16; c < seg * 16 + 16; c++) {
            float vv = ScT[c][row];
            float w = (vv >= thresh) ? expf(vv - mx) : 0.f;
            dsum += w;
            QT[c][row] = w;     // P^T
        }
        Vs[row][64 + seg] = dsum;
    }
    __syncthreads();
    {
        const float rd = 1.f / (Vs[row][64] + Vs[row][65] + Vs[row][66] + Vs[row][67]);
#pragma unroll
        for (int c = seg * 16; c < seg * 16 + 16; c++) QT[c][row] *= rd;
    }
    __syncthreads();
    {   // ctx[r][j] = sum_c P[r][c] * V[c][j]
        float acc[4][4] = {};
#pragma unroll 4
        for (int c = 0; c < 64; c++) {
            float4 p4 = *reinterpret_cast<const float4*>(&QT[c][tm]);
            float4 v4 = *reinterpret_cast<const float4*>(&Vs[c][tn]);
            const float p[4] = {p4.x, p4.y, p4.z, p4.w};
            const float b[4] = {v4.x, v4.y, v4.z, v4.w};
#pragma unroll
            for (int i = 0; i < 4; i++)
#pragma unroll
                for (int j = 0; j < 4; j++)
                    acc[i][j] += p[i] * b[j];
        }
#pragma unroll
        for (int i = 0; i < 4; i++) {
            ushort4 o;
            o.x = f2bf(acc[i][0]); o.y = f2bf(acc[i][1]);
            o.z = f2bf(acc[i][2]); o.w = f2bf(acc[i][3]);
            *reinterpret_cast<ushort4*>(
                &ctx[(size_t)(sl * 64 + tm + i) * 512 + hh * 64 + tn]) = o;
        }
    }
}

// ---------------------------------------------------------- fp32 GEMM (small)
template<int ACT, int PERM, int LN>
__global__ __launch_bounds__(256) void gemm_k(
    const float* __restrict__ A, int lda,
    const float* __restrict__ W, int ldw,
    const float* __restrict__ bias,
    const float* res,
    float* C, int ldc,
    int K,
    const float* __restrict__ stats,
    const float* __restrict__ lng, const float* __restrict__ lnb)
{
    __shared__ float As[16][68];
    __shared__ float Ws[16][68];
    __shared__ float ms[64], rss[64];
    const int row0 = blockIdx.y * 64;
    const int col0 = blockIdx.x * 64;
    const int tid = threadIdx.x;
    if (LN) {
        if (tid < 64) {
            ms[tid]  = stats[(row0 + tid) * 2];
            rss[tid] = stats[(row0 + tid) * 2 + 1];
        }
        __syncthreads();
    }
    const int tm = (tid >> 4) << 2;
    const int tn = (tid & 15) << 2;
    float acc[4][4] = {};
    for (int k0 = 0; k0 < K; k0 += 16) {
#pragma unroll
        for (int i = 0; i < 4; i++) {
            int idx = i * 256 + tid;
            int r = idx >> 4, kk = idx & 15;
            float v = A[(size_t)(row0 + r) * lda + (k0 + kk)];
            if (LN) v = (v - ms[r]) * rss[r] * lng[k0 + kk] + lnb[k0 + kk];
            As[kk][r] = v;
        }
#pragma unroll
        for (int i = 0; i < 4; i++) {
            int idx = i * 256 + tid;
            int kk = idx >> 6, c = idx & 63;
            Ws[kk][c] = W[(size_t)(k0 + kk) * ldw + (col0 + c)];
        }
        __syncthreads();
#pragma unroll
        for (int kk = 0; kk < 16; kk++) {
            float4 a4 = *reinterpret_cast<const float4*>(&As[kk][tm]);
            float4 b4 = *reinterpret_cast<const float4*>(&Ws[kk][tn]);
            const float a[4] = {a4.x, a4.y, a4.z, a4.w};
            const float b[4] = {b4.x, b4.y, b4.z, b4.w};
#pragma unroll
            for (int i = 0; i < 4; i++)
#pragma unroll
                for (int j = 0; j < 4; j++)
                    acc[i][j] += a[i] * b[j];
        }
        __syncthreads();
    }
#pragma unroll
    for (int i = 0; i < 4; i++) {
        int r = row0 + tm + i;
#pragma unroll
        for (int j = 0; j < 4; j++) {
            int c = col0 + tn + j;
            float v = acc[i][j];
            if (bias) v += bias[c];
            if (ACT == 1) v = gelu_exact(v);
            if (res) v += res[(size_t)r * ldc + c];
            if (PERM) {
                int bb = r & 63, ss = r >> 6;
                C[((size_t)bb * 512 + ss) * ldc + c] = v;
            } else {
                C[(size_t)r * ldc + c] = v;
            }
        }
    }
}

// ---------------------------------------------------------------- pool (+LN)
__global__ __launch_bounds__(512) void pool_ln_k(
    const float* __restrict__ h, const float* __restrict__ st,
    const float* __restrict__ gf, const float* __restrict__ bf,
    float* __restrict__ pooled)
{
    const int b = blockIdx.x;
    const int d = threadIdx.x;
    const float g = gf[d], bb = bf[d];
    float acc = 0.f;
    for (int s = 0; s < 512; s++) {
        int r = s * 64 + b;
        float m = st[r * 2], rs = st[r * 2 + 1];
        acc += (h[(size_t)r * 512 + d] - m) * rs * g + bb;
    }
    pooled[b * 512 + d] = acc * (1.f / 512.f);
}

// ---------------------------------------------------------------- host side
static void run_layer2(const float* const* p, int l,
                       float* h, unsigned short* hn_bf,
                       unsigned short* qkv, int chunk_rows,
                       unsigned short* f1c, int cw,
                       unsigned short* wqkv_t, unsigned short* wo_t,
                       unsigned short* f1_t, unsigned short* f2_t,
                       hipStream_t stream)
{
    const float* g1  = p[0] + l * 512;
    const float* b1  = p[1] + l * 512;
    const float* wq  = p[2] + (size_t)l * 262144;
    const float* wk  = p[3] + (size_t)l * 262144;
    const float* wv  = p[4] + (size_t)l * 262144;
    const float* wo  = p[5] + (size_t)l * 262144;
    const float* wob = p[6] + l * 512;
    const float* g2  = p[7] + l * 512;
    const float* b2  = p[8] + l * 512;
    const float* f1W = p[9] + (size_t)l * 1048576;
    const float* f1b = p[10] + l * 2048;
    const float* f2W = p[11] + (size_t)l * 1048576;
    const float* f2b = p[12] + l * 512;

    // all six weight transpose+casts in one dispatch
    {
        WTDesc d0 = {wq,  wqkv_t,          512,  512};
        WTDesc d1 = {wk,  wqkv_t + 262144, 512,  512};
        WTDesc d2 = {wv,  wqkv_t + 524288, 512,  512};
        WTDesc d3 = {wo,  wo_t,            512,  512};
        WTDesc d4 = {f1W, f1_t,            512,  2048};
        WTDesc d5 = {f2W, f2_t,            2048, 512};
        wtcast6_k<<<dim3(64, 64, 6), 256, 0, stream>>>(d0, d1, d2, d3, d4, d5);
    }

    // ---- attention block ----
    cast_ln_k<<<32768, 256, 0, stream>>>(h, g1, b1, hn_bf);
    for (int r0 = 0; r0 < 32768; r0 += chunk_rows) {
        mgemm_k<0, 1, 0, 0><<<dim3(chunk_rows / 128, 12), 256, 0, stream>>>(
            hn_bf + (size_t)r0 * 512, 512, wqkv_t, 512, nullptr,
            nullptr, nullptr, qkv, 1536, 512);
        attn2_k<<<(chunk_rows / 64) * 8, 256, 0, stream>>>(
            qkv, hn_bf + (size_t)r0 * 512);           // ctx overwrites hn_bf
    }
    mgemm_k<0, 0, 1, 1><<<dim3(256, 4), 256, 0, stream>>>(
        hn_bf, 512, wo_t, 512, wob, h, h, nullptr, 512, 512);

    // ---- FFN block ----
    cast_ln_k<<<32768, 256, 0, stream>>>(h, g2, b2, hn_bf);
    for (int c0 = 0; c0 < 2048; c0 += cw) {
        mgemm_k<1, 1, 0, 1><<<dim3(256, cw / 128), 256, 0, stream>>>(
            hn_bf, 512, f1_t + (size_t)c0 * 512, 512, f1b + c0,
            nullptr, nullptr, f1c, cw, 512);
        if (c0 == 0)
            mgemm_k<0, 0, 1, 1><<<dim3(256, 4), 256, 0, stream>>>(
                f1c, cw, f2_t + c0, 2048, f2b, h, h, nullptr, 512, cw);
        else
            mgemm_k<0, 0, 1, 0><<<dim3(256, 4), 256, 0, stream>>>(
                f1c, cw, f2_t + c0, 2048, nullptr, h, h, nullptr, 512, cw);
    }
}

extern "C" void kernel_launch(void* const* d_in, const int* in_sizes, int n_in,
                              void* d_out, int out_size, void* d_ws, size_t ws_size,
                              hipStream_t stream)
{
    const float* x       = (const float*)d_in[0];
    const float* enc_inW = (const float*)d_in[1];
    const float* enc_inb = (const float*)d_in[2];
    const float* mu_W    = (const float*)d_in[3];
    const float* mu_b    = (const float*)d_in[4];
    const float* lv_W    = (const float*)d_in[5];
    const float* lv_b    = (const float*)d_in[6];
    const float* dec_inW = (const float*)d_in[7];
    const float* dec_inb = (const float*)d_in[8];
    const float* out_W   = (const float*)d_in[9];
    const float* out_b   = (const float*)d_in[10];
    const float* const* ep = (const float* const*)(d_in + 11);
    const float* const* dp = (const float* const*)(d_in + 26);

    float* fout   = (float*)d_out;             // recon (64,512,64)
    float* mu_out = fout + 2097152;            // (64,128)
    float* lv_out = mu_out + 8192;             // (64,128)

    const size_t SZ = (size_t)32768 * 512;
    size_t off = 0;
    char* base = (char*)d_ws;
    auto take = [&](size_t bytes) -> char* {
        char* pp = base + off;
        off = (off + bytes + 255) & ~(size_t)255;
        return pp;
    };
    float*          h      = (float*)take(SZ * 4);            // 64 MB
    unsigned short* hn_bf  = (unsigned short*)take(SZ * 2);   // 32 MB
    unsigned short* wqkv_t = (unsigned short*)take(1536 * 512 * 2);
    unsigned short* wo_t   = (unsigned short*)take(512 * 512 * 2);
    unsigned short* f1_t   = (unsigned short*)take(2048 * 512 * 2);
    unsigned short* f2_t   = (unsigned short*)take(512 * 2048 * 2);
    float*          stats  = (float*)take(65536 * 4);
    float*          pooled = (float*)take(131072);
    float*          zemb   = (float*)take(131072);
    float*          pe     = (float*)take(512 * 512 * 4);     // 1 MB

    // shared scratch: qkv (attention phase) / f1 chunk (FFN phase)
    unsigned short* qkv; unsigned short* f1c;
    int chunk_rows, cw;
    size_t rem = (ws_size > off) ? (ws_size - off) : 0;
    const size_t F1_FULL  = (size_t)32768 * 2048 * 2;   // 128 MB
    const size_t QKV_FULL = (size_t)32768 * 1536 * 2;   // 96 MB
    if (rem >= F1_FULL + 512) {                 // single-dispatch FFN tier
        unsigned short* share = (unsigned short*)take(F1_FULL);
        qkv = share; f1c = share; chunk_rows = 32768; cw = 2048;
    } else if (rem >= QKV_FULL + 512) {
        unsigned short* share = (unsigned short*)take(QKV_FULL);
        qkv = share; f1c = share; chunk_rows = 32768; cw = 512;
    } else if (rem >= (size_t)32768 * 512 * 2 + 512) {
        unsigned short* share = (unsigned short*)take((size_t)32768 * 512 * 2);
        qkv = share; f1c = share; chunk_rows = 8192; cw = 512;
    } else {
        qkv = (unsigned short*)take((size_t)4096 * 1536 * 2);
        chunk_rows = 4096;
        f1c = (unsigned short*)fout; cw = 128;  // d_out recon = 8MB scratch
    }

    const int M = 32768;

    pe_k<<<512, 256, 0, stream>>>(pe);

    // ---------------- encoder ----------------
    embed_gemm_k<<<dim3(8, 512), 256, 0, stream>>>(x, enc_inW, enc_inb, pe, h);
    for (int l = 0; l < 2; l++)
        run_layer2(ep, l, h, hn_bf, qkv, chunk_rows, f1c, cw,
                   wqkv_t, wo_t, f1_t, f2_t, stream);

    // ---------------- latent ----------------
    stats_k<<<M, 256, 0, stream>>>(h, stats);
    pool_ln_k<<<64, 512, 0, stream>>>(h, stats, ep[13], ep[14], pooled);
    gemm_k<0, 0, 0><<<dim3(2, 1), 256, 0, stream>>>(pooled, 512, mu_W, 128, mu_b,
                                                    nullptr, mu_out, 128, 512,
                                                    nullptr, nullptr, nullptr);
    gemm_k<0, 0, 0><<<dim3(2, 1), 256, 0, stream>>>(pooled, 512, lv_W, 128, lv_b,
                                                    nullptr, lv_out, 128, 512,
                                                    nullptr, nullptr, nullptr);
    gemm_k<0, 0, 0><<<dim3(8, 1), 256, 0, stream>>>(mu_out, 128, dec_inW, 512, dec_inb,
                                                    nullptr, zemb, 512, 128,
                                                    nullptr, nullptr, nullptr);
    dec_embed_k<<<16384, 256, 0, stream>>>(zemb, pe, h);

    // ---------------- decoder ----------------
    for (int l = 0; l < 2; l++)
        run_layer2(dp, l, h, hn_bf, qkv, chunk_rows, f1c, cw,
                   wqkv_t, wo_t, f1_t, f2_t, stream);

    // final LN + out-proj, stored as (B,S,INP)
    stats_k<<<M, 256, 0, stream>>>(h, stats);
    gemm_k<0, 1, 1><<<dim3(1, M / 64), 256, 0, stream>>>(
        h, 512, out_W, 64, out_b, nullptr, fout, 64, 512, stats, dp[13], dp[14]);
}